// Round 5
// baseline (863.223 us; speedup 1.0000x reference)
//
#include <hip/hip_runtime.h>
#include <hip/hip_bf16.h>

#define N_NODES 50000
#define N_EDGES 800000
#define NPAD    50048   // nodes padded to multiple of 64
#define NCHUNK  49      // ceil(NPAD/1024)

typedef __attribute__((ext_vector_type(8))) short short8;
typedef __attribute__((ext_vector_type(4))) float f32x4;

static __device__ inline short f2bf(float f) {
    union { __hip_bfloat16 b; short s; } c; c.b = __float2bfloat16(f); return c.s;
}
static __device__ inline float bf2f(short s) {
    union { unsigned u; float f; } c; c.u = ((unsigned)(unsigned short)s) << 16; return c.f;
}
static __device__ inline float bflo(unsigned u) {
    union { unsigned v; float f; } c; c.v = u << 16; return c.f;
}
static __device__ inline float bfhi(unsigned u) {
    union { unsigned v; float f; } c; c.v = u & 0xffff0000u; return c.f;
}

// ---------------------------------------------------------------------------
// k_pack: bf16-ize inputs + prepack weights into MFMA B-fragment order.
// ALSO: histogram of edge targets into deg[].
// ---------------------------------------------------------------------------
__global__ __launch_bounds__(256) void k_pack(const float* __restrict__ x,
                                              const float* __restrict__ ids,
                                              const float* __restrict__ mW1,
                                              const float* __restrict__ mW2,
                                              const float* __restrict__ uW1,
                                              const float* __restrict__ uW2,
                                              const int* __restrict__ ei,
                                              int* __restrict__ deg,
                                              __hip_bfloat16* __restrict__ Xid,
                                              __hip_bfloat16* __restrict__ W1pk,
                                              __hip_bfloat16* __restrict__ W2pk,
                                              __hip_bfloat16* __restrict__ uW1pk,
                                              __hip_bfloat16* __restrict__ uW2pk) {
    const int tid = blockIdx.x * 256 + threadIdx.x;
    if (tid < N_EDGES) atomicAdd(&deg[ei[N_EDGES + tid]], 1);

    const int XN = NPAD * 96 / 8;
    if (tid < XN) {
        const int n = tid / 12, c0 = (tid % 12) * 8;
        short8 v;
#pragma unroll
        for (int i = 0; i < 8; ++i) {
            const int c = c0 + i;
            float f = 0.f;
            if (n < N_NODES) f = (c < 64) ? x[n * 64 + c] : ids[n * 32 + (c - 64)];
            v[i] = f2bf(f);
        }
        *(short8*)&Xid[n * 96 + c0] = v;
        return;
    }
    int r = tid - XN;
    if (r < 3 * 24 * 64) {  // msg-W1, K=96, NT=24 (cols 0..191 P1, 192..383 P2)
        const int kt = r / (24 * 64), nt = (r / 64) % 24, l = r % 64;
        const int e = l & 15, kg = l >> 4;
        short8 v;
#pragma unroll
        for (int i = 0; i < 8; ++i) {
            const int k = kt * 32 + kg * 8 + i;
            const int col = nt * 16 + e;
            float val;
            if (col < 192) { const int row = (k < 64) ? k : k + 64;  val = mW1[row * 192 + col]; }
            else           { const int row = (k < 64) ? k + 64 : k + 96; val = mW1[row * 192 + (col - 192)]; }
            v[i] = f2bf(val);
        }
        *(short8*)&W1pk[r * 8] = v;
        return;
    }
    r -= 3 * 24 * 64;
    if (r < 6 * 4 * 64) {  // msg-W2 [192,64]
        const int kt = r / (4 * 64), nt = (r / 64) % 4, l = r % 64;
        const int e = l & 15, kg = l >> 4;
        short8 v;
#pragma unroll
        for (int i = 0; i < 8; ++i)
            v[i] = f2bf(mW2[(kt * 32 + kg * 8 + i) * 64 + nt * 16 + e]);
        *(short8*)&W2pk[r * 8] = v;
        return;
    }
    r -= 6 * 4 * 64;
    if (r < 4 * 12 * 64) {  // uW1 [128,192]
        const int kt = r / (12 * 64), nt = (r / 64) % 12, l = r % 64;
        const int e = l & 15, kg = l >> 4;
        short8 v;
#pragma unroll
        for (int i = 0; i < 8; ++i)
            v[i] = f2bf(uW1[(kt * 32 + kg * 8 + i) * 192 + nt * 16 + e]);
        *(short8*)&uW1pk[r * 8] = v;
        return;
    }
    r -= 4 * 12 * 64;
    if (r < 6 * 8 * 64) {  // uW2 [192,128]
        const int kt = r / (8 * 64), nt = (r / 64) % 8, l = r % 64;
        const int e = l & 15, kg = l >> 4;
        short8 v;
#pragma unroll
        for (int i = 0; i < 8; ++i)
            v[i] = f2bf(uW2[(kt * 32 + kg * 8 + i) * 128 + nt * 16 + e]);
        *(short8*)&uW2pk[r * 8] = v;
    }
}

// ---------------------------------------------------------------------------
// Scan, 3 textbook kernels: block sums -> serial exclusive scan of sums ->
// per-block scan (serial LDS wave-combine, no divergent sub-scan).
// ---------------------------------------------------------------------------
__global__ __launch_bounds__(64) void k_scan1(const int* __restrict__ deg,
                                              int* __restrict__ bsum) {
    const int base = blockIdx.x * 1024, l = threadIdx.x;
    int s = 0;
#pragma unroll
    for (int q = 0; q < 16; ++q) {
        const int i = base + q * 64 + l;
        s += (i < NPAD) ? deg[i] : 0;
    }
#pragma unroll
    for (int off = 32; off; off >>= 1) s += __shfl_xor(s, off);
    if (l == 0) bsum[blockIdx.x] = s;
}

__global__ __launch_bounds__(64) void k_scan2(const int* __restrict__ bsum,
                                              int* __restrict__ bbase) {
    const int t = threadIdx.x;
    if (t < NCHUNK) {
        int s = 0;
        for (int q = 0; q < t; ++q) s += bsum[q];
        bbase[t] = s;
    }
}

__global__ __launch_bounds__(1024) void k_scan3(const int* __restrict__ deg,
                                                const int* __restrict__ bbase,
                                                int* __restrict__ cursor) {
    __shared__ int wtot[16];
    const int t = threadIdx.x, w = t >> 6, lane = t & 63;
    const int i = blockIdx.x * 1024 + t;
    const int v0 = (i < NPAD) ? deg[i] : 0;
    int v = v0;
#pragma unroll
    for (int off = 1; off < 64; off <<= 1) {
        const int n = __shfl_up(v, off);
        if (lane >= off) v += n;
    }
    if (lane == 63) wtot[w] = v;
    __syncthreads();
    int wbase = bbase[blockIdx.x];
    for (int q = 0; q < w; ++q) wbase += wtot[q];
    if (i < NPAD) cursor[i] = wbase + v - v0;
}

// ---------------------------------------------------------------------------
// k_scatter: permute edges into target-sorted order. (j,i) packed as int2.
// ---------------------------------------------------------------------------
__global__ __launch_bounds__(256) void k_scatter(const int* __restrict__ ei,
                                                 const float* __restrict__ ec,
                                                 int* __restrict__ cursor,
                                                 int2* __restrict__ sJI,
                                                 float* __restrict__ sEC) {
    const int e = blockIdx.x * 256 + threadIdx.x;
    if (e >= N_EDGES) return;
    const int i = ei[N_EDGES + e];
    const int pos = atomicAdd(&cursor[i], 1);
    sJI[pos] = make_int2(ei[e], i);
    sEC[pos] = ec[e];
}

// ---------------------------------------------------------------------------
// k_pre (MFMA): [P1|P2] = Xid[N,96] @ W1p[96,384] (+b1 on P1 half), bf16 out.
// ---------------------------------------------------------------------------
__global__ __launch_bounds__(256) void k_pre(const __hip_bfloat16* __restrict__ Xid,
                                             const __hip_bfloat16* __restrict__ W1pk,
                                             const float* __restrict__ b1,
                                             __hip_bfloat16* __restrict__ P1,
                                             __hip_bfloat16* __restrict__ P2) {
    const int t = threadIdx.x, w = t >> 6, l = t & 63;
    const int e = l & 15, kg = l >> 4;
    const int n0 = blockIdx.x * 64 + w * 16;

    short8 A[3];
#pragma unroll
    for (int kt = 0; kt < 3; ++kt)
        A[kt] = *(const short8*)&Xid[(n0 + e) * 96 + kt * 32 + kg * 8];

#pragma unroll
    for (int nt = 0; nt < 24; ++nt) {
        const float bv = (nt < 12) ? b1[nt * 16 + e] : 0.f;
        f32x4 acc = {bv, bv, bv, bv};
#pragma unroll
        for (int kt = 0; kt < 3; ++kt) {
            const short8 B = *(const short8*)&W1pk[((kt * 24 + nt) * 64 + l) * 8];
            acc = __builtin_amdgcn_mfma_f32_16x16x32_bf16(A[kt], B, acc, 0, 0, 0);
        }
#pragma unroll
        for (int r = 0; r < 4; ++r) {
            const int node = n0 + kg * 4 + r;
            if (node < N_NODES) {
                if (nt < 12) P1[node * 192 + nt * 16 + e] = __float2bfloat16(acc[r]);
                else         P2[node * 192 + (nt - 12) * 16 + e] = __float2bfloat16(acc[r]);
            }
        }
    }
}

// ---------------------------------------------------------------------------
// k_edge (MFMA, target-sorted edges): 16 edges/wave-iter. All 12 A-gathers
// hoisted (12 outstanding loads). Per-edge atomic epilogue (R3-identical).
// ---------------------------------------------------------------------------
#define GPB 25
__global__ __launch_bounds__(256) void k_edge(const int2* __restrict__ sJI,
                                              const float* __restrict__ sEC,
                                              const __hip_bfloat16* __restrict__ P1,
                                              const __hip_bfloat16* __restrict__ P2,
                                              const __hip_bfloat16* __restrict__ W2pk,
                                              const float* __restrict__ b2,
                                              float* __restrict__ agg) {
    __shared__ uint4 w2s[6 * 4 * 64];  // 24576 B, fragment-ordered
    const int t = threadIdx.x;
    for (int v = t; v < 1536; v += 256) w2s[v] = ((const uint4*)W2pk)[v];
    __syncthreads();

    const int w = t >> 6, l = t & 63;
    const int e = l & 15, kg = l >> 4;
    float b2v[4];
#pragma unroll
    for (int n = 0; n < 4; ++n) b2v[n] = b2[n * 16 + e];

    const int gEnd = blockIdx.x * GPB + GPB;  // 2000*25 == 50000 groups

    for (int g = blockIdx.x * GPB + w; g < gEnd; g += 4) {
        const int e0 = g * 16;
        const int2 ji = sJI[e0 + e];
        const int jj = ji.x, ii = ji.y;
        const __hip_bfloat16* r1 = P1 + (size_t)ii * 192 + kg * 8;
        const __hip_bfloat16* r2 = P2 + (size_t)jj * 192 + kg * 8;
        const float4 ecq = *(const float4*)(sEC + e0 + kg * 4);

        // Hoist all 12 gathers: 12 outstanding 16B loads per lane.
        union { uint4 q; unsigned u[4]; } A1[6], A2[6];
#pragma unroll
        for (int tt = 0; tt < 6; ++tt) {
            A1[tt].q = *(const uint4*)(r1 + tt * 32);
            A2[tt].q = *(const uint4*)(r2 + tt * 32);
        }

        f32x4 acc0 = {0.f, 0.f, 0.f, 0.f};
        f32x4 acc1 = {0.f, 0.f, 0.f, 0.f};
        f32x4 acc2 = {0.f, 0.f, 0.f, 0.f};
        f32x4 acc3 = {0.f, 0.f, 0.f, 0.f};

#pragma unroll
        for (int tt = 0; tt < 6; ++tt) {
            short8 h;
#pragma unroll
            for (int p = 0; p < 4; ++p) {
                float s0 = bflo(A1[tt].u[p]) + bflo(A2[tt].u[p]);
                float s1 = bfhi(A1[tt].u[p]) + bfhi(A2[tt].u[p]);
                s0 = s0 > 0.f ? s0 : 0.f;
                s1 = s1 > 0.f ? s1 : 0.f;
                h[2 * p]     = f2bf(s0);
                h[2 * p + 1] = f2bf(s1);
            }
            acc0 = __builtin_amdgcn_mfma_f32_16x16x32_bf16(h, *(const short8*)&w2s[(tt * 4 + 0) * 64 + l], acc0, 0, 0, 0);
            acc1 = __builtin_amdgcn_mfma_f32_16x16x32_bf16(h, *(const short8*)&w2s[(tt * 4 + 1) * 64 + l], acc1, 0, 0, 0);
            acc2 = __builtin_amdgcn_mfma_f32_16x16x32_bf16(h, *(const short8*)&w2s[(tt * 4 + 2) * 64 + l], acc2, 0, 0, 0);
            acc3 = __builtin_amdgcn_mfma_f32_16x16x32_bf16(h, *(const short8*)&w2s[(tt * 4 + 3) * 64 + l], acc3, 0, 0, 0);
        }

        // Per-edge atomic epilogue (R3-identical; sorted targets keep agg L2-local)
#pragma unroll
        for (int r = 0; r < 4; ++r) {
            const int edge = kg * 4 + r;
            const int it = __shfl(ii, edge);
            const float ecv = ((const float*)&ecq)[r];
            float v0 = (acc0[r] + b2v[0]) * ecv;
            float v1 = (acc1[r] + b2v[1]) * ecv;
            float v2 = (acc2[r] + b2v[2]) * ecv;
            float v3 = (acc3[r] + b2v[3]) * ecv;
            float* base = agg + (size_t)it * 64 + e;
            atomicAdd(base,      v0);
            atomicAdd(base + 16, v1);
            atomicAdd(base + 32, v2);
            atomicAdd(base + 48, v3);
        }
    }
}

// ---------------------------------------------------------------------------
// k_upd (fused MFMA): H = ReLU([x*nc|agg]@uW1+b1) in swizzled LDS, then
// out = H@uW2+b2.
// ---------------------------------------------------------------------------
__global__ __launch_bounds__(256) void k_upd(const __hip_bfloat16* __restrict__ Xid,
                                             const float* __restrict__ nc,
                                             const float* __restrict__ agg,
                                             const __hip_bfloat16* __restrict__ uW1pk,
                                             const float* __restrict__ ub1,
                                             const __hip_bfloat16* __restrict__ uW2pk,
                                             const float* __restrict__ ub2,
                                             float* __restrict__ out) {
    __shared__ char Hs[4][16 * 384];
    const int t = threadIdx.x, w = t >> 6, l = t & 63;
    const int e = l & 15, kg = l >> 4;
    const int n0 = blockIdx.x * 64 + w * 16;
    const int nodeA = n0 + e;

    const float ncv = nc[nodeA < N_NODES ? nodeA : N_NODES - 1];
    short8 A[4];
#pragma unroll
    for (int kt = 0; kt < 2; ++kt) {
        const short8 xa = *(const short8*)&Xid[nodeA * 96 + kt * 32 + kg * 8];
        short8 o;
#pragma unroll
        for (int i = 0; i < 8; ++i) o[i] = f2bf(bf2f(xa[i]) * ncv);
        A[kt] = o;
    }
#pragma unroll
    for (int kt = 2; kt < 4; ++kt) {
        const float* ap = agg + (size_t)nodeA * 64 + (kt - 2) * 32 + kg * 8;
        const float4 a0 = *(const float4*)ap;
        const float4 a1 = *(const float4*)(ap + 4);
        short8 o;
        o[0] = f2bf(a0.x); o[1] = f2bf(a0.y); o[2] = f2bf(a0.z); o[3] = f2bf(a0.w);
        o[4] = f2bf(a1.x); o[5] = f2bf(a1.y); o[6] = f2bf(a1.z); o[7] = f2bf(a1.w);
        A[kt] = o;
    }

#pragma unroll
    for (int nt = 0; nt < 12; ++nt) {
        const float bv = ub1[nt * 16 + e];
        f32x4 acc = {bv, bv, bv, bv};
#pragma unroll
        for (int kt = 0; kt < 4; ++kt) {
            const short8 B = *(const short8*)&uW1pk[((kt * 12 + nt) * 64 + l) * 8];
            acc = __builtin_amdgcn_mfma_f32_16x16x32_bf16(A[kt], B, acc, 0, 0, 0);
        }
#pragma unroll
        for (int r = 0; r < 4; ++r) {
            const int hr = kg * 4 + r;
            const float v = acc[r] > 0.f ? acc[r] : 0.f;
            int byte = hr * 384 + (nt * 16 + e) * 2;
            byte ^= (hr & 7) << 4;
            *(__hip_bfloat16*)(&Hs[w][0] + byte) = __float2bfloat16(v);
        }
    }

    short8 A2[6];
#pragma unroll
    for (int kt = 0; kt < 6; ++kt) {
        int byte = e * 384 + kt * 64 + kg * 16;
        byte ^= (e & 7) << 4;
        A2[kt] = *(const short8*)(&Hs[w][0] + byte);
    }
#pragma unroll
    for (int nt = 0; nt < 8; ++nt) {
        const float bv = ub2[nt * 16 + e];
        f32x4 acc = {bv, bv, bv, bv};
#pragma unroll
        for (int kt = 0; kt < 6; ++kt) {
            const short8 B = *(const short8*)&uW2pk[((kt * 8 + nt) * 64 + l) * 8];
            acc = __builtin_amdgcn_mfma_f32_16x16x32_bf16(A2[kt], B, acc, 0, 0, 0);
        }
#pragma unroll
        for (int r = 0; r < 4; ++r) {
            const int node = n0 + kg * 4 + r;
            if (node < N_NODES) out[node * 128 + nt * 16 + e] = acc[r];
        }
    }
}

extern "C" void kernel_launch(void* const* d_in, const int* in_sizes, int n_in,
                              void* d_out, int out_size, void* d_ws, size_t ws_size,
                              hipStream_t stream) {
    const float* x   = (const float*)d_in[0];
    const int*   ei  = (const int*)d_in[1];
    const float* ncv = (const float*)d_in[2];
    const float* ecv = (const float*)d_in[3];
    const float* ids = (const float*)d_in[4];
    const float* mW1 = (const float*)d_in[6];
    const float* mb1 = (const float*)d_in[7];
    const float* mW2 = (const float*)d_in[8];
    const float* mb2 = (const float*)d_in[9];
    const float* uW1 = (const float*)d_in[10];
    const float* ub1 = (const float*)d_in[11];
    const float* uW2 = (const float*)d_in[12];
    const float* ub2 = (const float*)d_in[13];
    float* out = (float*)d_out;

    char* ws = (char*)d_ws;
    __hip_bfloat16* Xid  = (__hip_bfloat16*)ws;   ws += (size_t)NPAD * 96 * 2;
    __hip_bfloat16* P1   = (__hip_bfloat16*)ws;   ws += (size_t)NPAD * 192 * 2;
    __hip_bfloat16* P2   = (__hip_bfloat16*)ws;   ws += (size_t)NPAD * 192 * 2;
    float*          agg  = (float*)ws;            ws += (size_t)NPAD * 64 * 4;
    __hip_bfloat16* W1pk = (__hip_bfloat16*)ws;   ws += 3 * 24 * 64 * 8 * 2;
    __hip_bfloat16* W2pk = (__hip_bfloat16*)ws;   ws += 6 * 4 * 64 * 8 * 2;
    __hip_bfloat16* uW1pk= (__hip_bfloat16*)ws;   ws += 4 * 12 * 64 * 8 * 2;
    __hip_bfloat16* uW2pk= (__hip_bfloat16*)ws;   ws += 6 * 8 * 64 * 8 * 2;
    int*            deg  = (int*)ws;              ws += (size_t)NPAD * 4;
    int*            cur  = (int*)ws;              ws += (size_t)NPAD * 4;
    int*            bsum = (int*)ws;              ws += 64 * 4;
    int*            bbas = (int*)ws;              ws += 64 * 4;
    int2*           sJI  = (int2*)ws;             ws += (size_t)N_EDGES * 8;
    float*          sEC  = (float*)ws;            ws += (size_t)N_EDGES * 4;

    hipMemsetAsync(agg, 0, (size_t)NPAD * 64 * sizeof(float), stream);
    hipMemsetAsync(deg, 0, (size_t)NPAD * sizeof(int), stream);

    const int packGrid = (N_EDGES + 255) / 256;  // covers pack work (612864) too
    k_pack<<<packGrid, 256, 0, stream>>>(x, ids, mW1, mW2, uW1, uW2, ei, deg,
                                         Xid, W1pk, W2pk, uW1pk, uW2pk);
    k_scan1<<<NCHUNK, 64, 0, stream>>>(deg, bsum);
    k_scan2<<<1, 64, 0, stream>>>(bsum, bbas);
    k_scan3<<<NCHUNK, 1024, 0, stream>>>(deg, bbas, cur);
    k_scatter<<<(N_EDGES + 255) / 256, 256, 0, stream>>>(ei, ecv, cur, sJI, sEC);
    k_pre<<<NPAD / 64, 256, 0, stream>>>(Xid, W1pk, mb1, P1, P2);
    k_edge<<<N_EDGES / 16 / GPB, 256, 0, stream>>>(sJI, sEC, P1, P2, W2pk, mb2, agg);
    k_upd<<<NPAD / 64, 256, 0, stream>>>(Xid, ncv, agg, uW1pk, ub1, uW2pk, ub2, out);
}

// Round 6
// 256.439 us; speedup vs baseline: 3.3662x; 3.3662x over previous
//
#include <hip/hip_runtime.h>
#include <hip/hip_bf16.h>

#define N_NODES 50000
#define N_EDGES 800000
#define NPAD    50048   // nodes padded to multiple of 64
#define NCHUNK  49      // ceil(NPAD/1024)

// k_edge span geometry: 625 blocks * 4 waves * 320 edges = 800000
#define EPWAVE 320      // edges per wave (contiguous in sorted order)
#define SLEN   80       // edges per stream (4 streams per wave, one per kg)
#define NITER  20       // SLEN/4 group-iterations per wave
#define NBLK_E 625

typedef __attribute__((ext_vector_type(8))) short short8;
typedef __attribute__((ext_vector_type(4))) float f32x4;

static __device__ inline short f2bf(float f) {
    union { __hip_bfloat16 b; short s; } c; c.b = __float2bfloat16(f); return c.s;
}
static __device__ inline float bf2f(short s) {
    union { unsigned u; float f; } c; c.u = ((unsigned)(unsigned short)s) << 16; return c.f;
}
static __device__ inline float bflo(unsigned u) {
    union { unsigned v; float f; } c; c.v = u << 16; return c.f;
}
static __device__ inline float bfhi(unsigned u) {
    union { unsigned v; float f; } c; c.v = u & 0xffff0000u; return c.f;
}

// ---------------------------------------------------------------------------
// k_pack: bf16-ize inputs + prepack weights into MFMA B-fragment order.
// ALSO: histogram of edge targets into deg[].
// ---------------------------------------------------------------------------
__global__ __launch_bounds__(256) void k_pack(const float* __restrict__ x,
                                              const float* __restrict__ ids,
                                              const float* __restrict__ mW1,
                                              const float* __restrict__ mW2,
                                              const float* __restrict__ uW1,
                                              const float* __restrict__ uW2,
                                              const int* __restrict__ ei,
                                              int* __restrict__ deg,
                                              __hip_bfloat16* __restrict__ Xid,
                                              __hip_bfloat16* __restrict__ W1pk,
                                              __hip_bfloat16* __restrict__ W2pk,
                                              __hip_bfloat16* __restrict__ uW1pk,
                                              __hip_bfloat16* __restrict__ uW2pk) {
    const int tid = blockIdx.x * 256 + threadIdx.x;
    if (tid < N_EDGES) atomicAdd(&deg[ei[N_EDGES + tid]], 1);

    const int XN = NPAD * 96 / 8;
    if (tid < XN) {
        const int n = tid / 12, c0 = (tid % 12) * 8;
        short8 v;
#pragma unroll
        for (int i = 0; i < 8; ++i) {
            const int c = c0 + i;
            float f = 0.f;
            if (n < N_NODES) f = (c < 64) ? x[n * 64 + c] : ids[n * 32 + (c - 64)];
            v[i] = f2bf(f);
        }
        *(short8*)&Xid[n * 96 + c0] = v;
        return;
    }
    int r = tid - XN;
    if (r < 3 * 24 * 64) {  // msg-W1, K=96, NT=24 (cols 0..191 P1, 192..383 P2)
        const int kt = r / (24 * 64), nt = (r / 64) % 24, l = r % 64;
        const int e = l & 15, kg = l >> 4;
        short8 v;
#pragma unroll
        for (int i = 0; i < 8; ++i) {
            const int k = kt * 32 + kg * 8 + i;
            const int col = nt * 16 + e;
            float val;
            if (col < 192) { const int row = (k < 64) ? k : k + 64;  val = mW1[row * 192 + col]; }
            else           { const int row = (k < 64) ? k + 64 : k + 96; val = mW1[row * 192 + (col - 192)]; }
            v[i] = f2bf(val);
        }
        *(short8*)&W1pk[r * 8] = v;
        return;
    }
    r -= 3 * 24 * 64;
    if (r < 6 * 4 * 64) {  // msg-W2 [192,64]
        const int kt = r / (4 * 64), nt = (r / 64) % 4, l = r % 64;
        const int e = l & 15, kg = l >> 4;
        short8 v;
#pragma unroll
        for (int i = 0; i < 8; ++i)
            v[i] = f2bf(mW2[(kt * 32 + kg * 8 + i) * 64 + nt * 16 + e]);
        *(short8*)&W2pk[r * 8] = v;
        return;
    }
    r -= 6 * 4 * 64;
    if (r < 4 * 12 * 64) {  // uW1 [128,192]
        const int kt = r / (12 * 64), nt = (r / 64) % 12, l = r % 64;
        const int e = l & 15, kg = l >> 4;
        short8 v;
#pragma unroll
        for (int i = 0; i < 8; ++i)
            v[i] = f2bf(uW1[(kt * 32 + kg * 8 + i) * 192 + nt * 16 + e]);
        *(short8*)&uW1pk[r * 8] = v;
        return;
    }
    r -= 4 * 12 * 64;
    if (r < 6 * 8 * 64) {  // uW2 [192,128]
        const int kt = r / (8 * 64), nt = (r / 64) % 8, l = r % 64;
        const int e = l & 15, kg = l >> 4;
        short8 v;
#pragma unroll
        for (int i = 0; i < 8; ++i)
            v[i] = f2bf(uW2[(kt * 32 + kg * 8 + i) * 128 + nt * 16 + e]);
        *(short8*)&uW2pk[r * 8] = v;
    }
}

// ---------------------------------------------------------------------------
// Scan, 3 textbook kernels (verified in R5).
// ---------------------------------------------------------------------------
__global__ __launch_bounds__(64) void k_scan1(const int* __restrict__ deg,
                                              int* __restrict__ bsum) {
    const int base = blockIdx.x * 1024, l = threadIdx.x;
    int s = 0;
#pragma unroll
    for (int q = 0; q < 16; ++q) {
        const int i = base + q * 64 + l;
        s += (i < NPAD) ? deg[i] : 0;
    }
#pragma unroll
    for (int off = 32; off; off >>= 1) s += __shfl_xor(s, off);
    if (l == 0) bsum[blockIdx.x] = s;
}

__global__ __launch_bounds__(64) void k_scan2(const int* __restrict__ bsum,
                                              int* __restrict__ bbase) {
    const int t = threadIdx.x;
    if (t < NCHUNK) {
        int s = 0;
        for (int q = 0; q < t; ++q) s += bsum[q];
        bbase[t] = s;
    }
}

__global__ __launch_bounds__(1024) void k_scan3(const int* __restrict__ deg,
                                                const int* __restrict__ bbase,
                                                int* __restrict__ cursor) {
    __shared__ int wtot[16];
    const int t = threadIdx.x, w = t >> 6, lane = t & 63;
    const int i = blockIdx.x * 1024 + t;
    const int v0 = (i < NPAD) ? deg[i] : 0;
    int v = v0;
#pragma unroll
    for (int off = 1; off < 64; off <<= 1) {
        const int n = __shfl_up(v, off);
        if (lane >= off) v += n;
    }
    if (lane == 63) wtot[w] = v;
    __syncthreads();
    int wbase = bbase[blockIdx.x];
    for (int q = 0; q < w; ++q) wbase += wtot[q];
    if (i < NPAD) cursor[i] = wbase + v - v0;
}

// ---------------------------------------------------------------------------
// k_scatter: permute edges into target-sorted order. (j,i) packed as int2.
// ---------------------------------------------------------------------------
__global__ __launch_bounds__(256) void k_scatter(const int* __restrict__ ei,
                                                 const float* __restrict__ ec,
                                                 int* __restrict__ cursor,
                                                 int2* __restrict__ sJI,
                                                 float* __restrict__ sEC) {
    const int e = blockIdx.x * 256 + threadIdx.x;
    if (e >= N_EDGES) return;
    const int i = ei[N_EDGES + e];
    const int pos = atomicAdd(&cursor[i], 1);
    sJI[pos] = make_int2(ei[e], i);
    sEC[pos] = ec[e];
}

// ---------------------------------------------------------------------------
// k_pre (MFMA): [P1|P2] = Xid[N,96] @ W1p[96,384] (+b1 on P1 half), bf16 out.
// ---------------------------------------------------------------------------
__global__ __launch_bounds__(256) void k_pre(const __hip_bfloat16* __restrict__ Xid,
                                             const __hip_bfloat16* __restrict__ W1pk,
                                             const float* __restrict__ b1,
                                             __hip_bfloat16* __restrict__ P1,
                                             __hip_bfloat16* __restrict__ P2) {
    const int t = threadIdx.x, w = t >> 6, l = t & 63;
    const int e = l & 15, kg = l >> 4;
    const int n0 = blockIdx.x * 64 + w * 16;

    short8 A[3];
#pragma unroll
    for (int kt = 0; kt < 3; ++kt)
        A[kt] = *(const short8*)&Xid[(n0 + e) * 96 + kt * 32 + kg * 8];

#pragma unroll
    for (int nt = 0; nt < 24; ++nt) {
        const float bv = (nt < 12) ? b1[nt * 16 + e] : 0.f;
        f32x4 acc = {bv, bv, bv, bv};
#pragma unroll
        for (int kt = 0; kt < 3; ++kt) {
            const short8 B = *(const short8*)&W1pk[((kt * 24 + nt) * 64 + l) * 8];
            acc = __builtin_amdgcn_mfma_f32_16x16x32_bf16(A[kt], B, acc, 0, 0, 0);
        }
#pragma unroll
        for (int r = 0; r < 4; ++r) {
            const int node = n0 + kg * 4 + r;
            if (node < N_NODES) {
                if (nt < 12) P1[node * 192 + nt * 16 + e] = __float2bfloat16(acc[r]);
                else         P2[node * 192 + (nt - 12) * 16 + e] = __float2bfloat16(acc[r]);
            }
        }
    }
}

// ---------------------------------------------------------------------------
// k_edge (MFMA, target-sorted, stream-per-quarter):
// Wave owns 320 contiguous sorted edges = 4 streams of 80 (stream kg feeds
// MFMA rows kg*4..kg*4+3). Each lane carries a running (curTarget, s0..s3)
// across iterations and flushes 4 atomics only on target change -> ~16x
// fewer atomics, and a target's flushes come from a single wave.
// ---------------------------------------------------------------------------
__global__ __launch_bounds__(256) void k_edge(const int2* __restrict__ sJI,
                                              const float* __restrict__ sEC,
                                              const __hip_bfloat16* __restrict__ P1,
                                              const __hip_bfloat16* __restrict__ P2,
                                              const __hip_bfloat16* __restrict__ W2pk,
                                              const float* __restrict__ b2,
                                              float* __restrict__ agg) {
    __shared__ uint4 w2s[6 * 4 * 64];  // 24576 B, fragment-ordered
    const int t = threadIdx.x;
    for (int v = t; v < 1536; v += 256) w2s[v] = ((const uint4*)W2pk)[v];
    __syncthreads();

    const int w = t >> 6, l = t & 63;
    const int e = l & 15, kg = l >> 4;
    float b2v[4];
#pragma unroll
    for (int n = 0; n < 4; ++n) b2v[n] = b2[n * 16 + e];

    const int waveBase = (blockIdx.x * 4 + w) * EPWAVE;
    // A-side: lane's row e = stream (e>>2), offset (e&3)
    const int aBase = waveBase + (e >> 2) * SLEN + (e & 3);
    // Output side: lane quarter kg owns stream kg
    const int oBase = waveBase + kg * SLEN;

    int curT = -1;
    float s0 = 0.f, s1 = 0.f, s2 = 0.f, s3 = 0.f;

    for (int iter = 0; iter < NITER; ++iter) {
        const int2 ji = sJI[aBase + iter * 4];
        const int jj = ji.x, ii = ji.y;
        const __hip_bfloat16* r1 = P1 + (size_t)ii * 192 + kg * 8;
        const __hip_bfloat16* r2 = P2 + (size_t)jj * 192 + kg * 8;

        union { uint4 q; unsigned u[4]; } A1[6], A2[6];
#pragma unroll
        for (int tt = 0; tt < 6; ++tt) {
            A1[tt].q = *(const uint4*)(r1 + tt * 32);
            A2[tt].q = *(const uint4*)(r2 + tt * 32);
        }

        f32x4 acc0 = {0.f, 0.f, 0.f, 0.f};
        f32x4 acc1 = {0.f, 0.f, 0.f, 0.f};
        f32x4 acc2 = {0.f, 0.f, 0.f, 0.f};
        f32x4 acc3 = {0.f, 0.f, 0.f, 0.f};

#pragma unroll
        for (int tt = 0; tt < 6; ++tt) {
            short8 h;
#pragma unroll
            for (int p = 0; p < 4; ++p) {
                float v0 = bflo(A1[tt].u[p]) + bflo(A2[tt].u[p]);
                float v1 = bfhi(A1[tt].u[p]) + bfhi(A2[tt].u[p]);
                v0 = v0 > 0.f ? v0 : 0.f;
                v1 = v1 > 0.f ? v1 : 0.f;
                h[2 * p]     = f2bf(v0);
                h[2 * p + 1] = f2bf(v1);
            }
            acc0 = __builtin_amdgcn_mfma_f32_16x16x32_bf16(h, *(const short8*)&w2s[(tt * 4 + 0) * 64 + l], acc0, 0, 0, 0);
            acc1 = __builtin_amdgcn_mfma_f32_16x16x32_bf16(h, *(const short8*)&w2s[(tt * 4 + 1) * 64 + l], acc1, 0, 0, 0);
            acc2 = __builtin_amdgcn_mfma_f32_16x16x32_bf16(h, *(const short8*)&w2s[(tt * 4 + 2) * 64 + l], acc2, 0, 0, 0);
            acc3 = __builtin_amdgcn_mfma_f32_16x16x32_bf16(h, *(const short8*)&w2s[(tt * 4 + 3) * 64 + l], acc3, 0, 0, 0);
        }

        // Segmented accumulate: row kg*4+r == edge oBase+iter*4+r, whose
        // target is held by A-side lane (kg*4+r) (lanes 0..15).
        const float4 ecq = *(const float4*)(sEC + oBase + iter * 4);
#pragma unroll
        for (int r = 0; r < 4; ++r) {
            const int tr = __shfl(ii, kg * 4 + r);
            if (tr != curT) {
                if (curT >= 0) {
                    float* base = agg + (size_t)curT * 64 + e;
                    atomicAdd(base,      s0);
                    atomicAdd(base + 16, s1);
                    atomicAdd(base + 32, s2);
                    atomicAdd(base + 48, s3);
                }
                s0 = s1 = s2 = s3 = 0.f;
                curT = tr;
            }
            const float ecv = ((const float*)&ecq)[r];
            s0 += (acc0[r] + b2v[0]) * ecv;
            s1 += (acc1[r] + b2v[1]) * ecv;
            s2 += (acc2[r] + b2v[2]) * ecv;
            s3 += (acc3[r] + b2v[3]) * ecv;
        }
    }
    {
        float* base = agg + (size_t)curT * 64 + e;
        atomicAdd(base,      s0);
        atomicAdd(base + 16, s1);
        atomicAdd(base + 32, s2);
        atomicAdd(base + 48, s3);
    }
}

// ---------------------------------------------------------------------------
// k_upd (fused MFMA): H = ReLU([x*nc|agg]@uW1+b1) in swizzled LDS, then
// out = H@uW2+b2.
// ---------------------------------------------------------------------------
__global__ __launch_bounds__(256) void k_upd(const __hip_bfloat16* __restrict__ Xid,
                                             const float* __restrict__ nc,
                                             const float* __restrict__ agg,
                                             const __hip_bfloat16* __restrict__ uW1pk,
                                             const float* __restrict__ ub1,
                                             const __hip_bfloat16* __restrict__ uW2pk,
                                             const float* __restrict__ ub2,
                                             float* __restrict__ out) {
    __shared__ char Hs[4][16 * 384];
    const int t = threadIdx.x, w = t >> 6, l = t & 63;
    const int e = l & 15, kg = l >> 4;
    const int n0 = blockIdx.x * 64 + w * 16;
    const int nodeA = n0 + e;

    const float ncv = nc[nodeA < N_NODES ? nodeA : N_NODES - 1];
    short8 A[4];
#pragma unroll
    for (int kt = 0; kt < 2; ++kt) {
        const short8 xa = *(const short8*)&Xid[nodeA * 96 + kt * 32 + kg * 8];
        short8 o;
#pragma unroll
        for (int i = 0; i < 8; ++i) o[i] = f2bf(bf2f(xa[i]) * ncv);
        A[kt] = o;
    }
#pragma unroll
    for (int kt = 2; kt < 4; ++kt) {
        const float* ap = agg + (size_t)nodeA * 64 + (kt - 2) * 32 + kg * 8;
        const float4 a0 = *(const float4*)ap;
        const float4 a1 = *(const float4*)(ap + 4);
        short8 o;
        o[0] = f2bf(a0.x); o[1] = f2bf(a0.y); o[2] = f2bf(a0.z); o[3] = f2bf(a0.w);
        o[4] = f2bf(a1.x); o[5] = f2bf(a1.y); o[6] = f2bf(a1.z); o[7] = f2bf(a1.w);
        A[kt] = o;
    }

#pragma unroll
    for (int nt = 0; nt < 12; ++nt) {
        const float bv = ub1[nt * 16 + e];
        f32x4 acc = {bv, bv, bv, bv};
#pragma unroll
        for (int kt = 0; kt < 4; ++kt) {
            const short8 B = *(const short8*)&uW1pk[((kt * 12 + nt) * 64 + l) * 8];
            acc = __builtin_amdgcn_mfma_f32_16x16x32_bf16(A[kt], B, acc, 0, 0, 0);
        }
#pragma unroll
        for (int r = 0; r < 4; ++r) {
            const int hr = kg * 4 + r;
            const float v = acc[r] > 0.f ? acc[r] : 0.f;
            int byte = hr * 384 + (nt * 16 + e) * 2;
            byte ^= (hr & 7) << 4;
            *(__hip_bfloat16*)(&Hs[w][0] + byte) = __float2bfloat16(v);
        }
    }

    short8 A2[6];
#pragma unroll
    for (int kt = 0; kt < 6; ++kt) {
        int byte = e * 384 + kt * 64 + kg * 16;
        byte ^= (e & 7) << 4;
        A2[kt] = *(const short8*)(&Hs[w][0] + byte);
    }
#pragma unroll
    for (int nt = 0; nt < 8; ++nt) {
        const float bv = ub2[nt * 16 + e];
        f32x4 acc = {bv, bv, bv, bv};
#pragma unroll
        for (int kt = 0; kt < 6; ++kt) {
            const short8 B = *(const short8*)&uW2pk[((kt * 8 + nt) * 64 + l) * 8];
            acc = __builtin_amdgcn_mfma_f32_16x16x32_bf16(A2[kt], B, acc, 0, 0, 0);
        }
#pragma unroll
        for (int r = 0; r < 4; ++r) {
            const int node = n0 + kg * 4 + r;
            if (node < N_NODES) out[node * 128 + nt * 16 + e] = acc[r];
        }
    }
}

extern "C" void kernel_launch(void* const* d_in, const int* in_sizes, int n_in,
                              void* d_out, int out_size, void* d_ws, size_t ws_size,
                              hipStream_t stream) {
    const float* x   = (const float*)d_in[0];
    const int*   ei  = (const int*)d_in[1];
    const float* ncv = (const float*)d_in[2];
    const float* ecv = (const float*)d_in[3];
    const float* ids = (const float*)d_in[4];
    const float* mW1 = (const float*)d_in[6];
    const float* mb1 = (const float*)d_in[7];
    const float* mW2 = (const float*)d_in[8];
    const float* mb2 = (const float*)d_in[9];
    const float* uW1 = (const float*)d_in[10];
    const float* ub1 = (const float*)d_in[11];
    const float* uW2 = (const float*)d_in[12];
    const float* ub2 = (const float*)d_in[13];
    float* out = (float*)d_out;

    char* ws = (char*)d_ws;
    __hip_bfloat16* Xid  = (__hip_bfloat16*)ws;   ws += (size_t)NPAD * 96 * 2;
    __hip_bfloat16* P1   = (__hip_bfloat16*)ws;   ws += (size_t)NPAD * 192 * 2;
    __hip_bfloat16* P2   = (__hip_bfloat16*)ws;   ws += (size_t)NPAD * 192 * 2;
    float*          agg  = (float*)ws;            ws += (size_t)NPAD * 64 * 4;
    __hip_bfloat16* W1pk = (__hip_bfloat16*)ws;   ws += 3 * 24 * 64 * 8 * 2;
    __hip_bfloat16* W2pk = (__hip_bfloat16*)ws;   ws += 6 * 4 * 64 * 8 * 2;
    __hip_bfloat16* uW1pk= (__hip_bfloat16*)ws;   ws += 4 * 12 * 64 * 8 * 2;
    __hip_bfloat16* uW2pk= (__hip_bfloat16*)ws;   ws += 6 * 8 * 64 * 8 * 2;
    int*            deg  = (int*)ws;              ws += (size_t)NPAD * 4;
    int*            cur  = (int*)ws;              ws += (size_t)NPAD * 4;
    int*            bsum = (int*)ws;              ws += 64 * 4;
    int*            bbas = (int*)ws;              ws += 64 * 4;
    int2*           sJI  = (int2*)ws;             ws += (size_t)N_EDGES * 8;
    float*          sEC  = (float*)ws;            ws += (size_t)N_EDGES * 4;

    hipMemsetAsync(agg, 0, (size_t)NPAD * 64 * sizeof(float), stream);
    hipMemsetAsync(deg, 0, (size_t)NPAD * sizeof(int), stream);

    const int packGrid = (N_EDGES + 255) / 256;  // covers pack work (612864) too
    k_pack<<<packGrid, 256, 0, stream>>>(x, ids, mW1, mW2, uW1, uW2, ei, deg,
                                         Xid, W1pk, W2pk, uW1pk, uW2pk);
    k_scan1<<<NCHUNK, 64, 0, stream>>>(deg, bsum);
    k_scan2<<<1, 64, 0, stream>>>(bsum, bbas);
    k_scan3<<<NCHUNK, 1024, 0, stream>>>(deg, bbas, cur);
    k_scatter<<<(N_EDGES + 255) / 256, 256, 0, stream>>>(ei, ecv, cur, sJI, sEC);
    k_pre<<<NPAD / 64, 256, 0, stream>>>(Xid, W1pk, mb1, P1, P2);
    k_edge<<<NBLK_E, 256, 0, stream>>>(sJI, sEC, P1, P2, W2pk, mb2, agg);
    k_upd<<<NPAD / 64, 256, 0, stream>>>(Xid, ncv, agg, uW1pk, ub1, uW2pk, ub2, out);
}

// Round 8
// 251.033 us; speedup vs baseline: 3.4387x; 1.0215x over previous
//
#include <hip/hip_runtime.h>
#include <hip/hip_bf16.h>

#define N_NODES 50000
#define N_EDGES 800000
#define NPAD    50048   // nodes padded to multiple of 64
#define NCHUNK  49      // ceil(NPAD/1024)

// k_edge span geometry: 1250 blocks * 4 waves * 160 edges = 800000
#define EPWAVE 160      // edges per wave (contiguous in sorted order)
#define SLEN   40       // edges per stream (4 streams per wave, one per kg)
#define NITER  10       // SLEN/4 group-iterations per wave (even, for unroll-2)
#define NBLK_E 1250

typedef __attribute__((ext_vector_type(8))) short short8;
typedef __attribute__((ext_vector_type(8))) _Float16 f16x8;
typedef __attribute__((ext_vector_type(4))) float f32x4;

static __device__ inline short f2bf(float f) {
    union { __hip_bfloat16 b; short s; } c; c.b = __float2bfloat16(f); return c.s;
}
static __device__ inline float bf2f(short s) {
    union { unsigned u; float f; } c; c.u = ((unsigned)(unsigned short)s) << 16; return c.f;
}

// ---------------------------------------------------------------------------
// k_pack: bf16-ize Xid + prepack weights into MFMA B-fragment order
// (W2 in fp16 for the f16 edge path). ALSO: histogram edge targets into deg[].
// ---------------------------------------------------------------------------
__global__ __launch_bounds__(256) void k_pack(const float* __restrict__ x,
                                              const float* __restrict__ ids,
                                              const float* __restrict__ mW1,
                                              const float* __restrict__ mW2,
                                              const float* __restrict__ uW1,
                                              const float* __restrict__ uW2,
                                              const int* __restrict__ ei,
                                              int* __restrict__ deg,
                                              __hip_bfloat16* __restrict__ Xid,
                                              __hip_bfloat16* __restrict__ W1pk,
                                              _Float16* __restrict__ W2pk,
                                              __hip_bfloat16* __restrict__ uW1pk,
                                              __hip_bfloat16* __restrict__ uW2pk) {
    const int tid = blockIdx.x * 256 + threadIdx.x;
    if (tid < N_EDGES) atomicAdd(&deg[ei[N_EDGES + tid]], 1);

    const int XN = NPAD * 96 / 8;
    if (tid < XN) {
        const int n = tid / 12, c0 = (tid % 12) * 8;
        short8 v;
#pragma unroll
        for (int i = 0; i < 8; ++i) {
            const int c = c0 + i;
            float f = 0.f;
            if (n < N_NODES) f = (c < 64) ? x[n * 64 + c] : ids[n * 32 + (c - 64)];
            v[i] = f2bf(f);
        }
        *(short8*)&Xid[n * 96 + c0] = v;
        return;
    }
    int r = tid - XN;
    if (r < 3 * 24 * 64) {  // msg-W1 (bf16), K=96, NT=24 (cols 0..191 P1, 192..383 P2)
        const int kt = r / (24 * 64), nt = (r / 64) % 24, l = r % 64;
        const int e = l & 15, kg = l >> 4;
        short8 v;
#pragma unroll
        for (int i = 0; i < 8; ++i) {
            const int k = kt * 32 + kg * 8 + i;
            const int col = nt * 16 + e;
            float val;
            if (col < 192) { const int row = (k < 64) ? k : k + 64;  val = mW1[row * 192 + col]; }
            else           { const int row = (k < 64) ? k + 64 : k + 96; val = mW1[row * 192 + (col - 192)]; }
            v[i] = f2bf(val);
        }
        *(short8*)&W1pk[r * 8] = v;
        return;
    }
    r -= 3 * 24 * 64;
    if (r < 6 * 4 * 64) {  // msg-W2 [192,64] -> fp16 frags
        const int kt = r / (4 * 64), nt = (r / 64) % 4, l = r % 64;
        const int e = l & 15, kg = l >> 4;
        f16x8 v;
#pragma unroll
        for (int i = 0; i < 8; ++i)
            v[i] = (_Float16)mW2[(kt * 32 + kg * 8 + i) * 64 + nt * 16 + e];
        *(f16x8*)&W2pk[r * 8] = v;
        return;
    }
    r -= 6 * 4 * 64;
    if (r < 4 * 12 * 64) {  // uW1 [128,192] (bf16)
        const int kt = r / (12 * 64), nt = (r / 64) % 12, l = r % 64;
        const int e = l & 15, kg = l >> 4;
        short8 v;
#pragma unroll
        for (int i = 0; i < 8; ++i)
            v[i] = f2bf(uW1[(kt * 32 + kg * 8 + i) * 192 + nt * 16 + e]);
        *(short8*)&uW1pk[r * 8] = v;
        return;
    }
    r -= 4 * 12 * 64;
    if (r < 6 * 8 * 64) {  // uW2 [192,128] (bf16)
        const int kt = r / (8 * 64), nt = (r / 64) % 8, l = r % 64;
        const int e = l & 15, kg = l >> 4;
        short8 v;
#pragma unroll
        for (int i = 0; i < 8; ++i)
            v[i] = f2bf(uW2[(kt * 32 + kg * 8 + i) * 128 + nt * 16 + e]);
        *(short8*)&uW2pk[r * 8] = v;
    }
}

// ---------------------------------------------------------------------------
// Scan: block sums, then per-block scan (block base = shfl-reduce of bsum).
// ---------------------------------------------------------------------------
__global__ __launch_bounds__(64) void k_scan1(const int* __restrict__ deg,
                                              int* __restrict__ bsum) {
    const int base = blockIdx.x * 1024, l = threadIdx.x;
    int s = 0;
#pragma unroll
    for (int q = 0; q < 16; ++q) {
        const int i = base + q * 64 + l;
        s += (i < NPAD) ? deg[i] : 0;
    }
#pragma unroll
    for (int off = 32; off; off >>= 1) s += __shfl_xor(s, off);
    if (l == 0) bsum[blockIdx.x] = s;
}

__global__ __launch_bounds__(1024) void k_scan3(const int* __restrict__ deg,
                                                const int* __restrict__ bsum,
                                                int* __restrict__ cursor) {
    __shared__ int wtot[16];
    __shared__ int blockBase;
    const int t = threadIdx.x, w = t >> 6, lane = t & 63;
    const int i = blockIdx.x * 1024 + t;
    const int v0 = (i < NPAD) ? deg[i] : 0;
    int v = v0;
#pragma unroll
    for (int off = 1; off < 64; off <<= 1) {
        const int n = __shfl_up(v, off);
        if (lane >= off) v += n;
    }
    if (lane == 63) wtot[w] = v;
    if (w == 0) {  // block base = sum of bsum[q] for q < blockIdx.x (NCHUNK<=64)
        int bv = (lane < blockIdx.x && lane < NCHUNK) ? bsum[lane] : 0;
#pragma unroll
        for (int off = 32; off; off >>= 1) bv += __shfl_xor(bv, off);
        if (lane == 0) blockBase = bv;
    }
    __syncthreads();
    int wbase = blockBase;
    for (int q = 0; q < w; ++q) wbase += wtot[q];
    if (i < NPAD) cursor[i] = wbase + v - v0;
}

// ---------------------------------------------------------------------------
// k_scatter: permute edges into target-sorted order. (j,i) packed as int2.
// ---------------------------------------------------------------------------
__global__ __launch_bounds__(256) void k_scatter(const int* __restrict__ ei,
                                                 const float* __restrict__ ec,
                                                 int* __restrict__ cursor,
                                                 int2* __restrict__ sJI,
                                                 float* __restrict__ sEC) {
    const int e = blockIdx.x * 256 + threadIdx.x;
    if (e >= N_EDGES) return;
    const int i = ei[N_EDGES + e];
    const int pos = atomicAdd(&cursor[i], 1);
    sJI[pos] = make_int2(ei[e], i);
    sEC[pos] = ec[e];
}

// ---------------------------------------------------------------------------
// k_pre (MFMA): [P1|P2] = Xid[N,96] @ W1p[96,384] (+b1 on P1 half), fp16 out.
// ---------------------------------------------------------------------------
__global__ __launch_bounds__(256) void k_pre(const __hip_bfloat16* __restrict__ Xid,
                                             const __hip_bfloat16* __restrict__ W1pk,
                                             const float* __restrict__ b1,
                                             _Float16* __restrict__ P1,
                                             _Float16* __restrict__ P2) {
    const int t = threadIdx.x, w = t >> 6, l = t & 63;
    const int e = l & 15, kg = l >> 4;
    const int n0 = blockIdx.x * 64 + w * 16;

    short8 A[3];
#pragma unroll
    for (int kt = 0; kt < 3; ++kt)
        A[kt] = *(const short8*)&Xid[(n0 + e) * 96 + kt * 32 + kg * 8];

#pragma unroll
    for (int nt = 0; nt < 24; ++nt) {
        const float bv = (nt < 12) ? b1[nt * 16 + e] : 0.f;
        f32x4 acc = {bv, bv, bv, bv};
#pragma unroll
        for (int kt = 0; kt < 3; ++kt) {
            const short8 B = *(const short8*)&W1pk[((kt * 24 + nt) * 64 + l) * 8];
            acc = __builtin_amdgcn_mfma_f32_16x16x32_bf16(A[kt], B, acc, 0, 0, 0);
        }
#pragma unroll
        for (int r = 0; r < 4; ++r) {
            const int node = n0 + kg * 4 + r;
            if (node < N_NODES) {
                if (nt < 12) P1[node * 192 + nt * 16 + e] = (_Float16)acc[r];
                else         P2[node * 192 + (nt - 12) * 16 + e] = (_Float16)acc[r];
            }
        }
    }
}

// ---------------------------------------------------------------------------
// k_edge (MFMA f16, target-sorted, stream-per-quarter, ping-pong pipelined):
// Wave owns 160 contiguous sorted edges = 4 streams of 40 (stream kg feeds
// MFMA rows kg*4..kg*4+3). h = ReLU(P1[i]+P2[j]) via v_pk_add/max_f16
// (clang vector elementwise ops). Segmented register accumulation; atomic
// flush only on target change.
// ---------------------------------------------------------------------------
union U16 { uint4 q; f16x8 f; };

#define EDGE_LOAD(A1, A2, JIV)                                                  \
  {                                                                             \
    const _Float16* r1 = P1 + (size_t)(JIV).y * 192 + kg * 8;                   \
    const _Float16* r2 = P2 + (size_t)(JIV).x * 192 + kg * 8;                   \
    _Pragma("unroll")                                                           \
    for (int tt = 0; tt < 6; ++tt) {                                            \
      A1[tt] = *(const uint4*)(r1 + tt * 32);                                   \
      A2[tt] = *(const uint4*)(r2 + tt * 32);                                   \
    }                                                                           \
  }

#define EDGE_COMPUTE(A1, A2, IIV, ITER)                                         \
  {                                                                             \
    f32x4 acc0 = {0.f,0.f,0.f,0.f}, acc1 = {0.f,0.f,0.f,0.f};                   \
    f32x4 acc2 = {0.f,0.f,0.f,0.f}, acc3 = {0.f,0.f,0.f,0.f};                   \
    _Pragma("unroll")                                                           \
    for (int tt = 0; tt < 6; ++tt) {                                            \
      U16 a1, a2;                                                               \
      a1.q = A1[tt]; a2.q = A2[tt];                                             \
      f16x8 hh = a1.f + a2.f;                                                   \
      hh = __builtin_elementwise_max(hh, (f16x8)(_Float16)0.f);                 \
      acc0 = __builtin_amdgcn_mfma_f32_16x16x32_f16(hh, *(const f16x8*)&w2s[(tt*4+0)*64 + l], acc0, 0, 0, 0); \
      acc1 = __builtin_amdgcn_mfma_f32_16x16x32_f16(hh, *(const f16x8*)&w2s[(tt*4+1)*64 + l], acc1, 0, 0, 0); \
      acc2 = __builtin_amdgcn_mfma_f32_16x16x32_f16(hh, *(const f16x8*)&w2s[(tt*4+2)*64 + l], acc2, 0, 0, 0); \
      acc3 = __builtin_amdgcn_mfma_f32_16x16x32_f16(hh, *(const f16x8*)&w2s[(tt*4+3)*64 + l], acc3, 0, 0, 0); \
    }                                                                           \
    const float4 ecq = *(const float4*)(sEC + oBase + (ITER) * 4);              \
    _Pragma("unroll")                                                           \
    for (int r = 0; r < 4; ++r) {                                               \
      const int tr = __shfl((IIV), kg * 4 + r);                                 \
      if (tr != curT) {                                                         \
        if (curT >= 0) {                                                        \
          float* fb = agg + (size_t)curT * 64 + e;                              \
          atomicAdd(fb,      s0); atomicAdd(fb + 16, s1);                       \
          atomicAdd(fb + 32, s2); atomicAdd(fb + 48, s3);                       \
        }                                                                       \
        s0 = s1 = s2 = s3 = 0.f;                                                \
        curT = tr;                                                              \
      }                                                                         \
      const float ecv = ((const float*)&ecq)[r];                                \
      s0 += (acc0[r] + b2v[0]) * ecv;                                           \
      s1 += (acc1[r] + b2v[1]) * ecv;                                           \
      s2 += (acc2[r] + b2v[2]) * ecv;                                           \
      s3 += (acc3[r] + b2v[3]) * ecv;                                           \
    }                                                                           \
  }

__global__ __launch_bounds__(256) void k_edge(const int2* __restrict__ sJI,
                                              const float* __restrict__ sEC,
                                              const _Float16* __restrict__ P1,
                                              const _Float16* __restrict__ P2,
                                              const _Float16* __restrict__ W2pk,
                                              const float* __restrict__ b2,
                                              float* __restrict__ agg) {
    __shared__ uint4 w2s[6 * 4 * 64];  // 24576 B, f16 fragment-ordered
    const int t = threadIdx.x;
    for (int v = t; v < 1536; v += 256) w2s[v] = ((const uint4*)W2pk)[v];
    __syncthreads();

    const int w = t >> 6, l = t & 63;
    const int e = l & 15, kg = l >> 4;
    float b2v[4];
#pragma unroll
    for (int n = 0; n < 4; ++n) b2v[n] = b2[n * 16 + e];

    const int waveBase = (blockIdx.x * 4 + w) * EPWAVE;
    const int aBase = waveBase + (e >> 2) * SLEN + (e & 3);  // A-side edge per lane
    const int oBase = waveBase + kg * SLEN;                  // output stream per quarter

    int curT = -1;
    float s0 = 0.f, s1 = 0.f, s2 = 0.f, s3 = 0.f;

    int2 jiA = sJI[aBase];
    uint4 A1a[6], A2a[6], A1b[6], A2b[6];
    EDGE_LOAD(A1a, A2a, jiA);

    for (int it = 0; it < NITER; it += 2) {
        const int2 jiB = sJI[aBase + (it + 1) * 4];
        EDGE_LOAD(A1b, A2b, jiB);
        EDGE_COMPUTE(A1a, A2a, jiA.y, it);
        if (it + 2 < NITER) {
            jiA = sJI[aBase + (it + 2) * 4];
            EDGE_LOAD(A1a, A2a, jiA);
        }
        EDGE_COMPUTE(A1b, A2b, jiB.y, it + 1);
    }
    {
        float* fb = agg + (size_t)curT * 64 + e;
        atomicAdd(fb,      s0); atomicAdd(fb + 16, s1);
        atomicAdd(fb + 32, s2); atomicAdd(fb + 48, s3);
    }
}

// ---------------------------------------------------------------------------
// k_upd (fused MFMA): H = ReLU([x*nc|agg]@uW1+b1) in swizzled LDS, then
// out = H@uW2+b2.
// ---------------------------------------------------------------------------
__global__ __launch_bounds__(256) void k_upd(const __hip_bfloat16* __restrict__ Xid,
                                             const float* __restrict__ nc,
                                             const float* __restrict__ agg,
                                             const __hip_bfloat16* __restrict__ uW1pk,
                                             const float* __restrict__ ub1,
                                             const __hip_bfloat16* __restrict__ uW2pk,
                                             const float* __restrict__ ub2,
                                             float* __restrict__ out) {
    __shared__ char Hs[4][16 * 384];
    const int t = threadIdx.x, w = t >> 6, l = t & 63;
    const int e = l & 15, kg = l >> 4;
    const int n0 = blockIdx.x * 64 + w * 16;
    const int nodeA = n0 + e;

    const float ncv = nc[nodeA < N_NODES ? nodeA : N_NODES - 1];
    short8 A[4];
#pragma unroll
    for (int kt = 0; kt < 2; ++kt) {
        const short8 xa = *(const short8*)&Xid[nodeA * 96 + kt * 32 + kg * 8];
        short8 o;
#pragma unroll
        for (int i = 0; i < 8; ++i) o[i] = f2bf(bf2f(xa[i]) * ncv);
        A[kt] = o;
    }
#pragma unroll
    for (int kt = 2; kt < 4; ++kt) {
        const float* ap = agg + (size_t)nodeA * 64 + (kt - 2) * 32 + kg * 8;
        const float4 a0 = *(const float4*)ap;
        const float4 a1 = *(const float4*)(ap + 4);
        short8 o;
        o[0] = f2bf(a0.x); o[1] = f2bf(a0.y); o[2] = f2bf(a0.z); o[3] = f2bf(a0.w);
        o[4] = f2bf(a1.x); o[5] = f2bf(a1.y); o[6] = f2bf(a1.z); o[7] = f2bf(a1.w);
        A[kt] = o;
    }

#pragma unroll
    for (int nt = 0; nt < 12; ++nt) {
        const float bv = ub1[nt * 16 + e];
        f32x4 acc = {bv, bv, bv, bv};
#pragma unroll
        for (int kt = 0; kt < 4; ++kt) {
            const short8 B = *(const short8*)&uW1pk[((kt * 12 + nt) * 64 + l) * 8];
            acc = __builtin_amdgcn_mfma_f32_16x16x32_bf16(A[kt], B, acc, 0, 0, 0);
        }
#pragma unroll
        for (int r = 0; r < 4; ++r) {
            const int hr = kg * 4 + r;
            const float v = acc[r] > 0.f ? acc[r] : 0.f;
            int byte = hr * 384 + (nt * 16 + e) * 2;
            byte ^= (hr & 7) << 4;
            *(__hip_bfloat16*)(&Hs[w][0] + byte) = __float2bfloat16(v);
        }
    }

    short8 A2[6];
#pragma unroll
    for (int kt = 0; kt < 6; ++kt) {
        int byte = e * 384 + kt * 64 + kg * 16;
        byte ^= (e & 7) << 4;
        A2[kt] = *(const short8*)(&Hs[w][0] + byte);
    }
#pragma unroll
    for (int nt = 0; nt < 8; ++nt) {
        const float bv = ub2[nt * 16 + e];
        f32x4 acc = {bv, bv, bv, bv};
#pragma unroll
        for (int kt = 0; kt < 6; ++kt) {
            const short8 B = *(const short8*)&uW2pk[((kt * 8 + nt) * 64 + l) * 8];
            acc = __builtin_amdgcn_mfma_f32_16x16x32_bf16(A2[kt], B, acc, 0, 0, 0);
        }
#pragma unroll
        for (int r = 0; r < 4; ++r) {
            const int node = n0 + kg * 4 + r;
            if (node < N_NODES) out[node * 128 + nt * 16 + e] = acc[r];
        }
    }
}

extern "C" void kernel_launch(void* const* d_in, const int* in_sizes, int n_in,
                              void* d_out, int out_size, void* d_ws, size_t ws_size,
                              hipStream_t stream) {
    const float* x   = (const float*)d_in[0];
    const int*   ei  = (const int*)d_in[1];
    const float* ncv = (const float*)d_in[2];
    const float* ecv = (const float*)d_in[3];
    const float* ids = (const float*)d_in[4];
    const float* mW1 = (const float*)d_in[6];
    const float* mb1 = (const float*)d_in[7];
    const float* mW2 = (const float*)d_in[8];
    const float* mb2 = (const float*)d_in[9];
    const float* uW1 = (const float*)d_in[10];
    const float* ub1 = (const float*)d_in[11];
    const float* uW2 = (const float*)d_in[12];
    const float* ub2 = (const float*)d_in[13];
    float* out = (float*)d_out;

    char* ws = (char*)d_ws;
    __hip_bfloat16* Xid  = (__hip_bfloat16*)ws;   ws += (size_t)NPAD * 96 * 2;
    _Float16*       P1   = (_Float16*)ws;         ws += (size_t)NPAD * 192 * 2;
    _Float16*       P2   = (_Float16*)ws;         ws += (size_t)NPAD * 192 * 2;
    float*          agg  = (float*)ws;            ws += (size_t)NPAD * 64 * 4;
    __hip_bfloat16* W1pk = (__hip_bfloat16*)ws;   ws += 3 * 24 * 64 * 8 * 2;
    _Float16*       W2pk = (_Float16*)ws;         ws += 6 * 4 * 64 * 8 * 2;
    __hip_bfloat16* uW1pk= (__hip_bfloat16*)ws;   ws += 4 * 12 * 64 * 8 * 2;
    __hip_bfloat16* uW2pk= (__hip_bfloat16*)ws;   ws += 6 * 8 * 64 * 8 * 2;
    int*            deg  = (int*)ws;              ws += (size_t)NPAD * 4;
    int*            cur  = (int*)ws;              ws += (size_t)NPAD * 4;
    int*            bsum = (int*)ws;              ws += 64 * 4;
    int2*           sJI  = (int2*)ws;             ws += (size_t)N_EDGES * 8;
    float*          sEC  = (float*)ws;            ws += (size_t)N_EDGES * 4;

    hipMemsetAsync(agg, 0, (size_t)NPAD * 64 * sizeof(float), stream);
    hipMemsetAsync(deg, 0, (size_t)NPAD * sizeof(int), stream);

    const int packGrid = (N_EDGES + 255) / 256;  // covers pack work (612864) too
    k_pack<<<packGrid, 256, 0, stream>>>(x, ids, mW1, mW2, uW1, uW2, ei, deg,
                                         Xid, W1pk, W2pk, uW1pk, uW2pk);
    k_scan1<<<NCHUNK, 64, 0, stream>>>(deg, bsum);
    k_scan3<<<NCHUNK, 1024, 0, stream>>>(deg, bsum, cur);
    k_scatter<<<(N_EDGES + 255) / 256, 256, 0, stream>>>(ei, ecv, cur, sJI, sEC);
    k_pre<<<NPAD / 64, 256, 0, stream>>>(Xid, W1pk, mb1, P1, P2);
    k_edge<<<NBLK_E, 256, 0, stream>>>(sJI, sEC, P1, P2, W2pk, mb2, agg);
    k_upd<<<NPAD / 64, 256, 0, stream>>>(Xid, ncv, agg, uW1pk, ub1, uW2pk, ub2, out);
}

// Round 12
// 250.971 us; speedup vs baseline: 3.4395x; 1.0002x over previous
//
#include <hip/hip_runtime.h>

#define N_NODES 50000
#define N_EDGES 800000
#define NPAD    50048   // nodes padded to multiple of 64
#define NCHUNK  49      // ceil(NPAD/1024)

// k_edge span geometry (R8-exact, known-good): 1250 blocks * 4 waves * 160 edges
#define EPWAVE 160      // edges per wave (contiguous in sorted order)
#define SLEN   40       // edges per stream (4 streams per wave, one per kg)
#define NITER  10       // SLEN/4 group-iterations per wave (even, for unroll-2)
#define NBLK_E 1250

typedef __attribute__((ext_vector_type(8))) _Float16 f16x8;
typedef __attribute__((ext_vector_type(4))) float f32x4;

// ---------------------------------------------------------------------------
// k_pack: f16-ize Xid + prepack ALL weights into MFMA B-fragment order (f16).
// ALSO: histogram edge targets into deg[].
// ---------------------------------------------------------------------------
__global__ __launch_bounds__(256) void k_pack(const float* __restrict__ x,
                                              const float* __restrict__ ids,
                                              const float* __restrict__ mW1,
                                              const float* __restrict__ mW2,
                                              const float* __restrict__ uW1,
                                              const float* __restrict__ uW2,
                                              const int* __restrict__ ei,
                                              int* __restrict__ deg,
                                              _Float16* __restrict__ Xid,
                                              _Float16* __restrict__ W1pk,
                                              _Float16* __restrict__ W2pk,
                                              _Float16* __restrict__ uW1pk,
                                              _Float16* __restrict__ uW2pk) {
    const int tid = blockIdx.x * 256 + threadIdx.x;
    if (tid < N_EDGES) atomicAdd(&deg[ei[N_EDGES + tid]], 1);

    const int XN = NPAD * 96 / 8;
    if (tid < XN) {
        const int n = tid / 12, c0 = (tid % 12) * 8;
        f16x8 v;
#pragma unroll
        for (int i = 0; i < 8; ++i) {
            const int c = c0 + i;
            float f = 0.f;
            if (n < N_NODES) f = (c < 64) ? x[n * 64 + c] : ids[n * 32 + (c - 64)];
            v[i] = (_Float16)f;
        }
        *(f16x8*)&Xid[n * 96 + c0] = v;
        return;
    }
    int r = tid - XN;
    if (r < 3 * 24 * 64) {  // msg-W1, K=96, NT=24 (cols 0..191 P1, 192..383 P2)
        const int kt = r / (24 * 64), nt = (r / 64) % 24, l = r % 64;
        const int e = l & 15, kg = l >> 4;
        f16x8 v;
#pragma unroll
        for (int i = 0; i < 8; ++i) {
            const int k = kt * 32 + kg * 8 + i;
            const int col = nt * 16 + e;
            float val;
            if (col < 192) { const int row = (k < 64) ? k : k + 64;  val = mW1[row * 192 + col]; }
            else           { const int row = (k < 64) ? k + 64 : k + 96; val = mW1[row * 192 + (col - 192)]; }
            v[i] = (_Float16)val;
        }
        *(f16x8*)&W1pk[r * 8] = v;
        return;
    }
    r -= 3 * 24 * 64;
    if (r < 6 * 4 * 64) {  // msg-W2 [192,64]
        const int kt = r / (4 * 64), nt = (r / 64) % 4, l = r % 64;
        const int e = l & 15, kg = l >> 4;
        f16x8 v;
#pragma unroll
        for (int i = 0; i < 8; ++i)
            v[i] = (_Float16)mW2[(kt * 32 + kg * 8 + i) * 64 + nt * 16 + e];
        *(f16x8*)&W2pk[r * 8] = v;
        return;
    }
    r -= 6 * 4 * 64;
    if (r < 4 * 12 * 64) {  // uW1 [128,192]
        const int kt = r / (12 * 64), nt = (r / 64) % 12, l = r % 64;
        const int e = l & 15, kg = l >> 4;
        f16x8 v;
#pragma unroll
        for (int i = 0; i < 8; ++i)
            v[i] = (_Float16)uW1[(kt * 32 + kg * 8 + i) * 192 + nt * 16 + e];
        *(f16x8*)&uW1pk[r * 8] = v;
        return;
    }
    r -= 4 * 12 * 64;
    if (r < 6 * 8 * 64) {  // uW2 [192,128]
        const int kt = r / (8 * 64), nt = (r / 64) % 8, l = r % 64;
        const int e = l & 15, kg = l >> 4;
        f16x8 v;
#pragma unroll
        for (int i = 0; i < 8; ++i)
            v[i] = (_Float16)uW2[(kt * 32 + kg * 8 + i) * 128 + nt * 16 + e];
        *(f16x8*)&uW2pk[r * 8] = v;
    }
}

// ---------------------------------------------------------------------------
// Scan: block sums, then per-block scan (block base = shfl-reduce of bsum).
// ---------------------------------------------------------------------------
__global__ __launch_bounds__(64) void k_scan1(const int* __restrict__ deg,
                                              int* __restrict__ bsum) {
    const int base = blockIdx.x * 1024, l = threadIdx.x;
    int s = 0;
#pragma unroll
    for (int q = 0; q < 16; ++q) {
        const int i = base + q * 64 + l;
        s += (i < NPAD) ? deg[i] : 0;
    }
#pragma unroll
    for (int off = 32; off; off >>= 1) s += __shfl_xor(s, off);
    if (l == 0) bsum[blockIdx.x] = s;
}

__global__ __launch_bounds__(1024) void k_scan3(const int* __restrict__ deg,
                                                const int* __restrict__ bsum,
                                                int* __restrict__ cursor) {
    __shared__ int wtot[16];
    __shared__ int blockBase;
    const int t = threadIdx.x, w = t >> 6, lane = t & 63;
    const int i = blockIdx.x * 1024 + t;
    const int v0 = (i < NPAD) ? deg[i] : 0;
    int v = v0;
#pragma unroll
    for (int off = 1; off < 64; off <<= 1) {
        const int n = __shfl_up(v, off);
        if (lane >= off) v += n;
    }
    if (lane == 63) wtot[w] = v;
    if (w == 0) {  // block base = sum of bsum[q] for q < blockIdx.x (NCHUNK<=64)
        int bv = (lane < blockIdx.x && lane < NCHUNK) ? bsum[lane] : 0;
#pragma unroll
        for (int off = 32; off; off >>= 1) bv += __shfl_xor(bv, off);
        if (lane == 0) blockBase = bv;
    }
    __syncthreads();
    int wbase = blockBase;
    for (int q = 0; q < w; ++q) wbase += wtot[q];
    if (i < NPAD) cursor[i] = wbase + v - v0;
}

// ---------------------------------------------------------------------------
// k_scatter: permute edges into target-sorted order. (j,i) packed as int2.
// ---------------------------------------------------------------------------
__global__ __launch_bounds__(256) void k_scatter(const int* __restrict__ ei,
                                                 const float* __restrict__ ec,
                                                 int* __restrict__ cursor,
                                                 int2* __restrict__ sJI,
                                                 float* __restrict__ sEC) {
    const int e = blockIdx.x * 256 + threadIdx.x;
    if (e >= N_EDGES) return;
    const int i = ei[N_EDGES + e];
    const int pos = atomicAdd(&cursor[i], 1);
    sJI[pos] = make_int2(ei[e], i);
    sEC[pos] = ec[e];
}

// ---------------------------------------------------------------------------
// k_pre (MFMA f16): [P1|P2] = Xid[N,96] @ W1p[96,384] (+b1 on P1 half).
// ---------------------------------------------------------------------------
__global__ __launch_bounds__(256) void k_pre(const _Float16* __restrict__ Xid,
                                             const _Float16* __restrict__ W1pk,
                                             const float* __restrict__ b1,
                                             _Float16* __restrict__ P1,
                                             _Float16* __restrict__ P2) {
    const int t = threadIdx.x, w = t >> 6, l = t & 63;
    const int e = l & 15, kg = l >> 4;
    const int n0 = blockIdx.x * 64 + w * 16;

    f16x8 A[3];
#pragma unroll
    for (int kt = 0; kt < 3; ++kt)
        A[kt] = *(const f16x8*)&Xid[(n0 + e) * 96 + kt * 32 + kg * 8];

#pragma unroll
    for (int nt = 0; nt < 24; ++nt) {
        const float bv = (nt < 12) ? b1[nt * 16 + e] : 0.f;
        f32x4 acc = {bv, bv, bv, bv};
#pragma unroll
        for (int kt = 0; kt < 3; ++kt) {
            const f16x8 B = *(const f16x8*)&W1pk[((kt * 24 + nt) * 64 + l) * 8];
            acc = __builtin_amdgcn_mfma_f32_16x16x32_f16(A[kt], B, acc, 0, 0, 0);
        }
#pragma unroll
        for (int r = 0; r < 4; ++r) {
            const int node = n0 + kg * 4 + r;
            if (node < N_NODES) {
                if (nt < 12) P1[node * 192 + nt * 16 + e] = (_Float16)acc[r];
                else         P2[node * 192 + (nt - 12) * 16 + e] = (_Float16)acc[r];
            }
        }
    }
}

// ---------------------------------------------------------------------------
// k_edge (MFMA f16, target-sorted, stream-per-quarter, ping-pong pipelined):
// R8-exact. Wave owns 160 contiguous sorted edges = 4 streams of 40.
// h = ReLU(P1[i]+P2[j]) via pk f16 ops. Segmented register accumulation;
// atomic flush only on target change.
// ---------------------------------------------------------------------------
union U16 { uint4 q; f16x8 f; };

#define EDGE_LOAD(A1, A2, JIV)                                                  \
  {                                                                             \
    const _Float16* r1 = P1 + (size_t)(JIV).y * 192 + kg * 8;                   \
    const _Float16* r2 = P2 + (size_t)(JIV).x * 192 + kg * 8;                   \
    _Pragma("unroll")                                                           \
    for (int tt = 0; tt < 6; ++tt) {                                            \
      A1[tt] = *(const uint4*)(r1 + tt * 32);                                   \
      A2[tt] = *(const uint4*)(r2 + tt * 32);                                   \
    }                                                                           \
  }

#define EDGE_COMPUTE(A1, A2, IIV, ITER)                                         \
  {                                                                             \
    f32x4 acc0 = {0.f,0.f,0.f,0.f}, acc1 = {0.f,0.f,0.f,0.f};                   \
    f32x4 acc2 = {0.f,0.f,0.f,0.f}, acc3 = {0.f,0.f,0.f,0.f};                   \
    _Pragma("unroll")                                                           \
    for (int tt = 0; tt < 6; ++tt) {                                            \
      U16 a1, a2;                                                               \
      a1.q = A1[tt]; a2.q = A2[tt];                                             \
      f16x8 hh = a1.f + a2.f;                                                   \
      hh = __builtin_elementwise_max(hh, (f16x8)(_Float16)0.f);                 \
      acc0 = __builtin_amdgcn_mfma_f32_16x16x32_f16(hh, *(const f16x8*)&w2s[(tt*4+0)*64 + l], acc0, 0, 0, 0); \
      acc1 = __builtin_amdgcn_mfma_f32_16x16x32_f16(hh, *(const f16x8*)&w2s[(tt*4+1)*64 + l], acc1, 0, 0, 0); \
      acc2 = __builtin_amdgcn_mfma_f32_16x16x32_f16(hh, *(const f16x8*)&w2s[(tt*4+2)*64 + l], acc2, 0, 0, 0); \
      acc3 = __builtin_amdgcn_mfma_f32_16x16x32_f16(hh, *(const f16x8*)&w2s[(tt*4+3)*64 + l], acc3, 0, 0, 0); \
    }                                                                           \
    const float4 ecq = *(const float4*)(sEC + oBase + (ITER) * 4);              \
    _Pragma("unroll")                                                           \
    for (int r = 0; r < 4; ++r) {                                               \
      const int tr = __shfl((IIV), kg * 4 + r);                                 \
      if (tr != curT) {                                                         \
        if (curT >= 0) {                                                        \
          float* fb = agg + (size_t)curT * 64 + e;                              \
          atomicAdd(fb,      s0); atomicAdd(fb + 16, s1);                       \
          atomicAdd(fb + 32, s2); atomicAdd(fb + 48, s3);                       \
        }                                                                       \
        s0 = s1 = s2 = s3 = 0.f;                                                \
        curT = tr;                                                              \
      }                                                                         \
      const float ecv = ((const float*)&ecq)[r];                                \
      s0 += (acc0[r] + b2v[0]) * ecv;                                           \
      s1 += (acc1[r] + b2v[1]) * ecv;                                           \
      s2 += (acc2[r] + b2v[2]) * ecv;                                           \
      s3 += (acc3[r] + b2v[3]) * ecv;                                           \
    }                                                                           \
  }

__global__ __launch_bounds__(256) void k_edge(const int2* __restrict__ sJI,
                                              const float* __restrict__ sEC,
                                              const _Float16* __restrict__ P1,
                                              const _Float16* __restrict__ P2,
                                              const _Float16* __restrict__ W2pk,
                                              const float* __restrict__ b2,
                                              float* __restrict__ agg) {
    __shared__ uint4 w2s[6 * 4 * 64];  // 24576 B, f16 fragment-ordered
    const int t = threadIdx.x;
    for (int v = t; v < 1536; v += 256) w2s[v] = ((const uint4*)W2pk)[v];
    __syncthreads();

    const int w = t >> 6, l = t & 63;
    const int e = l & 15, kg = l >> 4;
    float b2v[4];
#pragma unroll
    for (int n = 0; n < 4; ++n) b2v[n] = b2[n * 16 + e];

    const int waveBase = (blockIdx.x * 4 + w) * EPWAVE;
    const int aBase = waveBase + (e >> 2) * SLEN + (e & 3);  // A-side edge per lane
    const int oBase = waveBase + kg * SLEN;                  // output stream per quarter

    int curT = -1;
    float s0 = 0.f, s1 = 0.f, s2 = 0.f, s3 = 0.f;

    int2 jiA = sJI[aBase];
    uint4 A1a[6], A2a[6], A1b[6], A2b[6];
    EDGE_LOAD(A1a, A2a, jiA);

    for (int it = 0; it < NITER; it += 2) {
        const int2 jiB = sJI[aBase + (it + 1) * 4];
        EDGE_LOAD(A1b, A2b, jiB);
        EDGE_COMPUTE(A1a, A2a, jiA.y, it);
        if (it + 2 < NITER) {
            jiA = sJI[aBase + (it + 2) * 4];
            EDGE_LOAD(A1a, A2a, jiA);
        }
        EDGE_COMPUTE(A1b, A2b, jiB.y, it + 1);
    }
    {
        float* fb = agg + (size_t)curT * 64 + e;
        atomicAdd(fb,      s0); atomicAdd(fb + 16, s1);
        atomicAdd(fb + 32, s2); atomicAdd(fb + 48, s3);
    }
}

// ---------------------------------------------------------------------------
// k_upd (fused MFMA f16): H = ReLU([x*nc|agg]@uW1+b1) in swizzled LDS, then
// out = H@uW2+b2.
// ---------------------------------------------------------------------------
__global__ __launch_bounds__(256) void k_upd(const _Float16* __restrict__ Xid,
                                             const float* __restrict__ nc,
                                             const float* __restrict__ agg,
                                             const _Float16* __restrict__ uW1pk,
                                             const float* __restrict__ ub1,
                                             const _Float16* __restrict__ uW2pk,
                                             const float* __restrict__ ub2,
                                             float* __restrict__ out) {
    __shared__ char Hs[4][16 * 384];
    const int t = threadIdx.x, w = t >> 6, l = t & 63;
    const int e = l & 15, kg = l >> 4;
    const int n0 = blockIdx.x * 64 + w * 16;
    const int nodeA = n0 + e;

    const float ncv = nc[nodeA < N_NODES ? nodeA : N_NODES - 1];
    f16x8 A[4];
#pragma unroll
    for (int kt = 0; kt < 2; ++kt) {
        const f16x8 xa = *(const f16x8*)&Xid[nodeA * 96 + kt * 32 + kg * 8];
        f16x8 o;
#pragma unroll
        for (int i = 0; i < 8; ++i) o[i] = (_Float16)((float)xa[i] * ncv);
        A[kt] = o;
    }
#pragma unroll
    for (int kt = 2; kt < 4; ++kt) {
        const float* ap = agg + (size_t)nodeA * 64 + (kt - 2) * 32 + kg * 8;
        const float4 a0 = *(const float4*)ap;
        const float4 a1 = *(const float4*)(ap + 4);
        f16x8 o;
        o[0] = (_Float16)a0.x; o[1] = (_Float16)a0.y; o[2] = (_Float16)a0.z; o[3] = (_Float16)a0.w;
        o[4] = (_Float16)a1.x; o[5] = (_Float16)a1.y; o[6] = (_Float16)a1.z; o[7] = (_Float16)a1.w;
        A[kt] = o;
    }

#pragma unroll
    for (int nt = 0; nt < 12; ++nt) {
        const float bv = ub1[nt * 16 + e];
        f32x4 acc = {bv, bv, bv, bv};
#pragma unroll
        for (int kt = 0; kt < 4; ++kt) {
            const f16x8 B = *(const f16x8*)&uW1pk[((kt * 12 + nt) * 64 + l) * 8];
            acc = __builtin_amdgcn_mfma_f32_16x16x32_f16(A[kt], B, acc, 0, 0, 0);
        }
#pragma unroll
        for (int r = 0; r < 4; ++r) {
            const int hr = kg * 4 + r;
            const float v = acc[r] > 0.f ? acc[r] : 0.f;
            int byte = hr * 384 + (nt * 16 + e) * 2;
            byte ^= (hr & 7) << 4;
            *(_Float16*)(&Hs[w][0] + byte) = (_Float16)v;
        }
    }

    f16x8 A2[6];
#pragma unroll
    for (int kt = 0; kt < 6; ++kt) {
        int byte = e * 384 + kt * 64 + kg * 16;
        byte ^= (e & 7) << 4;
        A2[kt] = *(const f16x8*)(&Hs[w][0] + byte);
    }
#pragma unroll
    for (int nt = 0; nt < 8; ++nt) {
        const float bv = ub2[nt * 16 + e];
        f32x4 acc = {bv, bv, bv, bv};
#pragma unroll
        for (int kt = 0; kt < 6; ++kt) {
            const f16x8 B = *(const f16x8*)&uW2pk[((kt * 8 + nt) * 64 + l) * 8];
            acc = __builtin_amdgcn_mfma_f32_16x16x32_f16(A2[kt], B, acc, 0, 0, 0);
        }
#pragma unroll
        for (int r = 0; r < 4; ++r) {
            const int node = n0 + kg * 4 + r;
            if (node < N_NODES) out[node * 128 + nt * 16 + e] = acc[r];
        }
    }
}

extern "C" void kernel_launch(void* const* d_in, const int* in_sizes, int n_in,
                              void* d_out, int out_size, void* d_ws, size_t ws_size,
                              hipStream_t stream) {
    const float* x   = (const float*)d_in[0];
    const int*   ei  = (const int*)d_in[1];
    const float* ncv = (const float*)d_in[2];
    const float* ecv = (const float*)d_in[3];
    const float* ids = (const float*)d_in[4];
    const float* mW1 = (const float*)d_in[6];
    const float* mb1 = (const float*)d_in[7];
    const float* mW2 = (const float*)d_in[8];
    const float* mb2 = (const float*)d_in[9];
    const float* uW1 = (const float*)d_in[10];
    const float* ub1 = (const float*)d_in[11];
    const float* uW2 = (const float*)d_in[12];
    const float* ub2 = (const float*)d_in[13];
    float* out = (float*)d_out;

    char* ws = (char*)d_ws;
    _Float16*       Xid  = (_Float16*)ws;         ws += (size_t)NPAD * 96 * 2;
    _Float16*       P1   = (_Float16*)ws;         ws += (size_t)NPAD * 192 * 2;
    _Float16*       P2   = (_Float16*)ws;         ws += (size_t)NPAD * 192 * 2;
    float*          agg  = (float*)ws;            ws += (size_t)NPAD * 64 * 4;
    _Float16*       W1pk = (_Float16*)ws;         ws += 3 * 24 * 64 * 8 * 2;
    _Float16*       W2pk = (_Float16*)ws;         ws += 6 * 4 * 64 * 8 * 2;
    _Float16*       uW1pk= (_Float16*)ws;         ws += 4 * 12 * 64 * 8 * 2;
    _Float16*       uW2pk= (_Float16*)ws;         ws += 6 * 8 * 64 * 8 * 2;
    int*            deg  = (int*)ws;              ws += (size_t)NPAD * 4;
    int*            cur  = (int*)ws;              ws += (size_t)NPAD * 4;
    int*            bsum = (int*)ws;              ws += 64 * 4;
    int2*           sJI  = (int2*)ws;             ws += (size_t)N_EDGES * 8;
    float*          sEC  = (float*)ws;            ws += (size_t)N_EDGES * 4;

    hipMemsetAsync(agg, 0, (size_t)NPAD * 64 * sizeof(float), stream);
    hipMemsetAsync(deg, 0, (size_t)NPAD * sizeof(int), stream);

    const int packGrid = (N_EDGES + 255) / 256;  // covers pack work (612864) too
    k_pack<<<packGrid, 256, 0, stream>>>(x, ids, mW1, mW2, uW1, uW2, ei, deg,
                                         Xid, W1pk, W2pk, uW1pk, uW2pk);
    k_scan1<<<NCHUNK, 64, 0, stream>>>(deg, bsum);
    k_scan3<<<NCHUNK, 1024, 0, stream>>>(deg, bsum, cur);
    k_scatter<<<(N_EDGES + 255) / 256, 256, 0, stream>>>(ei, ecv, cur, sJI, sEC);
    k_pre<<<NPAD / 64, 256, 0, stream>>>(Xid, W1pk, mb1, P1, P2);
    k_edge<<<NBLK_E, 256, 0, stream>>>(sJI, sEC, P1, P2, W2pk, mb2, agg);
    k_upd<<<NPAD / 64, 256, 0, stream>>>(Xid, ncv, agg, uW1pk, ub1, uW2pk, ub2, out);
}

// Round 13
// 247.561 us; speedup vs baseline: 3.4869x; 1.0138x over previous
//
#include <hip/hip_runtime.h>

#define N_NODES 50000
#define N_EDGES 800000
#define NPAD    50048   // nodes padded to multiple of 64
#define NCHUNK  49      // ceil(NPAD/1024)

// k_edge span geometry (R8-exact, known-good): 1250 blocks * 4 waves * 160 edges
#define EPWAVE 160      // edges per wave (contiguous in sorted order)
#define SLEN   40       // edges per stream (4 streams per wave, one per kg)
#define NITER  10       // SLEN/4 group-iterations per wave (even, for unroll-2)
#define NBLK_E 1250

#define SCAT_BLK 3125   // k_mid blocks doing scatter (800000/256)
#define PRE_BLK  782    // k_mid blocks doing pre (NPAD/64)

typedef __attribute__((ext_vector_type(8))) _Float16 f16x8;
typedef __attribute__((ext_vector_type(4))) float f32x4;

// ---------------------------------------------------------------------------
// k_pack: f16-ize Xid + prepack ALL weights into MFMA B-fragment order (f16).
// ALSO: histogram edge targets into deg[].
// ---------------------------------------------------------------------------
__global__ __launch_bounds__(256) void k_pack(const float* __restrict__ x,
                                              const float* __restrict__ ids,
                                              const float* __restrict__ mW1,
                                              const float* __restrict__ mW2,
                                              const float* __restrict__ uW1,
                                              const float* __restrict__ uW2,
                                              const int* __restrict__ ei,
                                              int* __restrict__ deg,
                                              _Float16* __restrict__ Xid,
                                              _Float16* __restrict__ W1pk,
                                              _Float16* __restrict__ W2pk,
                                              _Float16* __restrict__ uW1pk,
                                              _Float16* __restrict__ uW2pk) {
    const int tid = blockIdx.x * 256 + threadIdx.x;
    if (tid < N_EDGES) atomicAdd(&deg[ei[N_EDGES + tid]], 1);

    const int XN = NPAD * 96 / 8;
    if (tid < XN) {
        const int n = tid / 12, c0 = (tid % 12) * 8;
        f16x8 v;
#pragma unroll
        for (int i = 0; i < 8; ++i) {
            const int c = c0 + i;
            float f = 0.f;
            if (n < N_NODES) f = (c < 64) ? x[n * 64 + c] : ids[n * 32 + (c - 64)];
            v[i] = (_Float16)f;
        }
        *(f16x8*)&Xid[n * 96 + c0] = v;
        return;
    }
    int r = tid - XN;
    if (r < 3 * 24 * 64) {  // msg-W1, K=96, NT=24 (cols 0..191 P1, 192..383 P2)
        const int kt = r / (24 * 64), nt = (r / 64) % 24, l = r % 64;
        const int e = l & 15, kg = l >> 4;
        f16x8 v;
#pragma unroll
        for (int i = 0; i < 8; ++i) {
            const int k = kt * 32 + kg * 8 + i;
            const int col = nt * 16 + e;
            float val;
            if (col < 192) { const int row = (k < 64) ? k : k + 64;  val = mW1[row * 192 + col]; }
            else           { const int row = (k < 64) ? k + 64 : k + 96; val = mW1[row * 192 + (col - 192)]; }
            v[i] = (_Float16)val;
        }
        *(f16x8*)&W1pk[r * 8] = v;
        return;
    }
    r -= 3 * 24 * 64;
    if (r < 6 * 4 * 64) {  // msg-W2 [192,64]
        const int kt = r / (4 * 64), nt = (r / 64) % 4, l = r % 64;
        const int e = l & 15, kg = l >> 4;
        f16x8 v;
#pragma unroll
        for (int i = 0; i < 8; ++i)
            v[i] = (_Float16)mW2[(kt * 32 + kg * 8 + i) * 64 + nt * 16 + e];
        *(f16x8*)&W2pk[r * 8] = v;
        return;
    }
    r -= 6 * 4 * 64;
    if (r < 4 * 12 * 64) {  // uW1 [128,192]
        const int kt = r / (12 * 64), nt = (r / 64) % 12, l = r % 64;
        const int e = l & 15, kg = l >> 4;
        f16x8 v;
#pragma unroll
        for (int i = 0; i < 8; ++i)
            v[i] = (_Float16)uW1[(kt * 32 + kg * 8 + i) * 192 + nt * 16 + e];
        *(f16x8*)&uW1pk[r * 8] = v;
        return;
    }
    r -= 4 * 12 * 64;
    if (r < 6 * 8 * 64) {  // uW2 [192,128]
        const int kt = r / (8 * 64), nt = (r / 64) % 8, l = r % 64;
        const int e = l & 15, kg = l >> 4;
        f16x8 v;
#pragma unroll
        for (int i = 0; i < 8; ++i)
            v[i] = (_Float16)uW2[(kt * 32 + kg * 8 + i) * 128 + nt * 16 + e];
        *(f16x8*)&uW2pk[r * 8] = v;
    }
}

// ---------------------------------------------------------------------------
// Scan: block sums, then per-block scan (block base = shfl-reduce of bsum).
// ---------------------------------------------------------------------------
__global__ __launch_bounds__(64) void k_scan1(const int* __restrict__ deg,
                                              int* __restrict__ bsum) {
    const int base = blockIdx.x * 1024, l = threadIdx.x;
    int s = 0;
#pragma unroll
    for (int q = 0; q < 16; ++q) {
        const int i = base + q * 64 + l;
        s += (i < NPAD) ? deg[i] : 0;
    }
#pragma unroll
    for (int off = 32; off; off >>= 1) s += __shfl_xor(s, off);
    if (l == 0) bsum[blockIdx.x] = s;
}

__global__ __launch_bounds__(1024) void k_scan3(const int* __restrict__ deg,
                                                const int* __restrict__ bsum,
                                                int* __restrict__ cursor) {
    __shared__ int wtot[16];
    __shared__ int blockBase;
    const int t = threadIdx.x, w = t >> 6, lane = t & 63;
    const int i = blockIdx.x * 1024 + t;
    const int v0 = (i < NPAD) ? deg[i] : 0;
    int v = v0;
#pragma unroll
    for (int off = 1; off < 64; off <<= 1) {
        const int n = __shfl_up(v, off);
        if (lane >= off) v += n;
    }
    if (lane == 63) wtot[w] = v;
    if (w == 0) {  // block base = sum of bsum[q] for q < blockIdx.x (NCHUNK<=64)
        int bv = (lane < blockIdx.x && lane < NCHUNK) ? bsum[lane] : 0;
#pragma unroll
        for (int off = 32; off; off >>= 1) bv += __shfl_xor(bv, off);
        if (lane == 0) blockBase = bv;
    }
    __syncthreads();
    int wbase = blockBase;
    for (int q = 0; q < w; ++q) wbase += wtot[q];
    if (i < NPAD) cursor[i] = wbase + v - v0;
}

// ---------------------------------------------------------------------------
// k_mid: merged independent launches (verbatim bodies).
//  blocks [0, SCAT_BLK): scatter edges into target-sorted order.
//  blocks [SCAT_BLK, SCAT_BLK+PRE_BLK): k_pre — [P1|P2] = Xid@W1p (+b1).
// ---------------------------------------------------------------------------
__global__ __launch_bounds__(256) void k_mid(const int* __restrict__ ei,
                                             const float* __restrict__ ec,
                                             int* __restrict__ cursor,
                                             int2* __restrict__ sJI,
                                             float* __restrict__ sEC,
                                             const _Float16* __restrict__ Xid,
                                             const _Float16* __restrict__ W1pk,
                                             const float* __restrict__ b1,
                                             _Float16* __restrict__ P1,
                                             _Float16* __restrict__ P2) {
    if (blockIdx.x < SCAT_BLK) {
        // ---- scatter body (verbatim from k_scatter) ----
        const int e = blockIdx.x * 256 + threadIdx.x;
        if (e >= N_EDGES) return;
        const int i = ei[N_EDGES + e];
        const int pos = atomicAdd(&cursor[i], 1);
        sJI[pos] = make_int2(ei[e], i);
        sEC[pos] = ec[e];
        return;
    }
    // ---- pre body (verbatim from k_pre; blockIdx.x -> bid) ----
    const int bid = blockIdx.x - SCAT_BLK;
    const int t = threadIdx.x, w = t >> 6, l = t & 63;
    const int e = l & 15, kg = l >> 4;
    const int n0 = bid * 64 + w * 16;

    f16x8 A[3];
#pragma unroll
    for (int kt = 0; kt < 3; ++kt)
        A[kt] = *(const f16x8*)&Xid[(n0 + e) * 96 + kt * 32 + kg * 8];

#pragma unroll
    for (int nt = 0; nt < 24; ++nt) {
        const float bv = (nt < 12) ? b1[nt * 16 + e] : 0.f;
        f32x4 acc = {bv, bv, bv, bv};
#pragma unroll
        for (int kt = 0; kt < 3; ++kt) {
            const f16x8 B = *(const f16x8*)&W1pk[((kt * 24 + nt) * 64 + l) * 8];
            acc = __builtin_amdgcn_mfma_f32_16x16x32_f16(A[kt], B, acc, 0, 0, 0);
        }
#pragma unroll
        for (int r = 0; r < 4; ++r) {
            const int node = n0 + kg * 4 + r;
            if (node < N_NODES) {
                if (nt < 12) P1[node * 192 + nt * 16 + e] = (_Float16)acc[r];
                else         P2[node * 192 + (nt - 12) * 16 + e] = (_Float16)acc[r];
            }
        }
    }
}

// ---------------------------------------------------------------------------
// k_edge (MFMA f16, target-sorted, stream-per-quarter, ping-pong pipelined):
// FROZEN R8/R12 structure. Wave owns 160 contiguous sorted edges = 4 streams
// of 40. h = ReLU(P1[i]+P2[j]) via pk f16 ops. Segmented register
// accumulation; atomic flush only on target change.
// ---------------------------------------------------------------------------
union U16 { uint4 q; f16x8 f; };

#define EDGE_LOAD(A1, A2, JIV)                                                  \
  {                                                                             \
    const _Float16* r1 = P1 + (size_t)(JIV).y * 192 + kg * 8;                   \
    const _Float16* r2 = P2 + (size_t)(JIV).x * 192 + kg * 8;                   \
    _Pragma("unroll")                                                           \
    for (int tt = 0; tt < 6; ++tt) {                                            \
      A1[tt] = *(const uint4*)(r1 + tt * 32);                                   \
      A2[tt] = *(const uint4*)(r2 + tt * 32);                                   \
    }                                                                           \
  }

#define EDGE_COMPUTE(A1, A2, IIV, ITER)                                         \
  {                                                                             \
    f32x4 acc0 = {0.f,0.f,0.f,0.f}, acc1 = {0.f,0.f,0.f,0.f};                   \
    f32x4 acc2 = {0.f,0.f,0.f,0.f}, acc3 = {0.f,0.f,0.f,0.f};                   \
    _Pragma("unroll")                                                           \
    for (int tt = 0; tt < 6; ++tt) {                                            \
      U16 a1, a2;                                                               \
      a1.q = A1[tt]; a2.q = A2[tt];                                             \
      f16x8 hh = a1.f + a2.f;                                                   \
      hh = __builtin_elementwise_max(hh, (f16x8)(_Float16)0.f);                 \
      acc0 = __builtin_amdgcn_mfma_f32_16x16x32_f16(hh, *(const f16x8*)&w2s[(tt*4+0)*64 + l], acc0, 0, 0, 0); \
      acc1 = __builtin_amdgcn_mfma_f32_16x16x32_f16(hh, *(const f16x8*)&w2s[(tt*4+1)*64 + l], acc1, 0, 0, 0); \
      acc2 = __builtin_amdgcn_mfma_f32_16x16x32_f16(hh, *(const f16x8*)&w2s[(tt*4+2)*64 + l], acc2, 0, 0, 0); \
      acc3 = __builtin_amdgcn_mfma_f32_16x16x32_f16(hh, *(const f16x8*)&w2s[(tt*4+3)*64 + l], acc3, 0, 0, 0); \
    }                                                                           \
    const float4 ecq = *(const float4*)(sEC + oBase + (ITER) * 4);              \
    _Pragma("unroll")                                                           \
    for (int r = 0; r < 4; ++r) {                                               \
      const int tr = __shfl((IIV), kg * 4 + r);                                 \
      if (tr != curT) {                                                         \
        if (curT >= 0) {                                                        \
          float* fb = agg + (size_t)curT * 64 + e;                              \
          atomicAdd(fb,      s0); atomicAdd(fb + 16, s1);                       \
          atomicAdd(fb + 32, s2); atomicAdd(fb + 48, s3);                       \
        }                                                                       \
        s0 = s1 = s2 = s3 = 0.f;                                                \
        curT = tr;                                                              \
      }                                                                         \
      const float ecv = ((const float*)&ecq)[r];                                \
      s0 += (acc0[r] + b2v[0]) * ecv;                                           \
      s1 += (acc1[r] + b2v[1]) * ecv;                                           \
      s2 += (acc2[r] + b2v[2]) * ecv;                                           \
      s3 += (acc3[r] + b2v[3]) * ecv;                                           \
    }                                                                           \
  }

__global__ __launch_bounds__(256) void k_edge(const int2* __restrict__ sJI,
                                              const float* __restrict__ sEC,
                                              const _Float16* __restrict__ P1,
                                              const _Float16* __restrict__ P2,
                                              const _Float16* __restrict__ W2pk,
                                              const float* __restrict__ b2,
                                              float* __restrict__ agg) {
    __shared__ uint4 w2s[6 * 4 * 64];  // 24576 B, f16 fragment-ordered
    const int t = threadIdx.x;
    for (int v = t; v < 1536; v += 256) w2s[v] = ((const uint4*)W2pk)[v];
    __syncthreads();

    const int w = t >> 6, l = t & 63;
    const int e = l & 15, kg = l >> 4;
    float b2v[4];
#pragma unroll
    for (int n = 0; n < 4; ++n) b2v[n] = b2[n * 16 + e];

    const int waveBase = (blockIdx.x * 4 + w) * EPWAVE;
    const int aBase = waveBase + (e >> 2) * SLEN + (e & 3);  // A-side edge per lane
    const int oBase = waveBase + kg * SLEN;                  // output stream per quarter

    int curT = -1;
    float s0 = 0.f, s1 = 0.f, s2 = 0.f, s3 = 0.f;

    int2 jiA = sJI[aBase];
    uint4 A1a[6], A2a[6], A1b[6], A2b[6];
    EDGE_LOAD(A1a, A2a, jiA);

    for (int it = 0; it < NITER; it += 2) {
        const int2 jiB = sJI[aBase + (it + 1) * 4];
        EDGE_LOAD(A1b, A2b, jiB);
        EDGE_COMPUTE(A1a, A2a, jiA.y, it);
        if (it + 2 < NITER) {
            jiA = sJI[aBase + (it + 2) * 4];
            EDGE_LOAD(A1a, A2a, jiA);
        }
        EDGE_COMPUTE(A1b, A2b, jiB.y, it + 1);
    }
    {
        float* fb = agg + (size_t)curT * 64 + e;
        atomicAdd(fb,      s0); atomicAdd(fb + 16, s1);
        atomicAdd(fb + 32, s2); atomicAdd(fb + 48, s3);
    }
}

// ---------------------------------------------------------------------------
// k_upd (fused MFMA f16): H = ReLU([x*nc|agg]@uW1+b1) in swizzled LDS, then
// out = H@uW2+b2.
// ---------------------------------------------------------------------------
__global__ __launch_bounds__(256) void k_upd(const _Float16* __restrict__ Xid,
                                             const float* __restrict__ nc,
                                             const float* __restrict__ agg,
                                             const _Float16* __restrict__ uW1pk,
                                             const float* __restrict__ ub1,
                                             const _Float16* __restrict__ uW2pk,
                                             const float* __restrict__ ub2,
                                             float* __restrict__ out) {
    __shared__ char Hs[4][16 * 384];
    const int t = threadIdx.x, w = t >> 6, l = t & 63;
    const int e = l & 15, kg = l >> 4;
    const int n0 = blockIdx.x * 64 + w * 16;
    const int nodeA = n0 + e;

    const float ncv = nc[nodeA < N_NODES ? nodeA : N_NODES - 1];
    f16x8 A[4];
#pragma unroll
    for (int kt = 0; kt < 2; ++kt) {
        const f16x8 xa = *(const f16x8*)&Xid[nodeA * 96 + kt * 32 + kg * 8];
        f16x8 o;
#pragma unroll
        for (int i = 0; i < 8; ++i) o[i] = (_Float16)((float)xa[i] * ncv);
        A[kt] = o;
    }
#pragma unroll
    for (int kt = 2; kt < 4; ++kt) {
        const float* ap = agg + (size_t)nodeA * 64 + (kt - 2) * 32 + kg * 8;
        const float4 a0 = *(const float4*)ap;
        const float4 a1 = *(const float4*)(ap + 4);
        f16x8 o;
        o[0] = (_Float16)a0.x; o[1] = (_Float16)a0.y; o[2] = (_Float16)a0.z; o[3] = (_Float16)a0.w;
        o[4] = (_Float16)a1.x; o[5] = (_Float16)a1.y; o[6] = (_Float16)a1.z; o[7] = (_Float16)a1.w;
        A[kt] = o;
    }

#pragma unroll
    for (int nt = 0; nt < 12; ++nt) {
        const float bv = ub1[nt * 16 + e];
        f32x4 acc = {bv, bv, bv, bv};
#pragma unroll
        for (int kt = 0; kt < 4; ++kt) {
            const f16x8 B = *(const f16x8*)&uW1pk[((kt * 12 + nt) * 64 + l) * 8];
            acc = __builtin_amdgcn_mfma_f32_16x16x32_f16(A[kt], B, acc, 0, 0, 0);
        }
#pragma unroll
        for (int r = 0; r < 4; ++r) {
            const int hr = kg * 4 + r;
            const float v = acc[r] > 0.f ? acc[r] : 0.f;
            int byte = hr * 384 + (nt * 16 + e) * 2;
            byte ^= (hr & 7) << 4;
            *(_Float16*)(&Hs[w][0] + byte) = (_Float16)v;
        }
    }

    f16x8 A2[6];
#pragma unroll
    for (int kt = 0; kt < 6; ++kt) {
        int byte = e * 384 + kt * 64 + kg * 16;
        byte ^= (e & 7) << 4;
        A2[kt] = *(const f16x8*)(&Hs[w][0] + byte);
    }
#pragma unroll
    for (int nt = 0; nt < 8; ++nt) {
        const float bv = ub2[nt * 16 + e];
        f32x4 acc = {bv, bv, bv, bv};
#pragma unroll
        for (int kt = 0; kt < 6; ++kt) {
            const f16x8 B = *(const f16x8*)&uW2pk[((kt * 8 + nt) * 64 + l) * 8];
            acc = __builtin_amdgcn_mfma_f32_16x16x32_f16(A2[kt], B, acc, 0, 0, 0);
        }
#pragma unroll
        for (int r = 0; r < 4; ++r) {
            const int node = n0 + kg * 4 + r;
            if (node < N_NODES) out[node * 128 + nt * 16 + e] = acc[r];
        }
    }
}

extern "C" void kernel_launch(void* const* d_in, const int* in_sizes, int n_in,
                              void* d_out, int out_size, void* d_ws, size_t ws_size,
                              hipStream_t stream) {
    const float* x   = (const float*)d_in[0];
    const int*   ei  = (const int*)d_in[1];
    const float* ncv = (const float*)d_in[2];
    const float* ecv = (const float*)d_in[3];
    const float* ids = (const float*)d_in[4];
    const float* mW1 = (const float*)d_in[6];
    const float* mb1 = (const float*)d_in[7];
    const float* mW2 = (const float*)d_in[8];
    const float* mb2 = (const float*)d_in[9];
    const float* uW1 = (const float*)d_in[10];
    const float* ub1 = (const float*)d_in[11];
    const float* uW2 = (const float*)d_in[12];
    const float* ub2 = (const float*)d_in[13];
    float* out = (float*)d_out;

    char* ws = (char*)d_ws;
    _Float16*       Xid  = (_Float16*)ws;         ws += (size_t)NPAD * 96 * 2;
    _Float16*       P1   = (_Float16*)ws;         ws += (size_t)NPAD * 192 * 2;
    _Float16*       P2   = (_Float16*)ws;         ws += (size_t)NPAD * 192 * 2;
    float*          agg  = (float*)ws;            ws += (size_t)NPAD * 64 * 4;
    _Float16*       W1pk = (_Float16*)ws;         ws += 3 * 24 * 64 * 8 * 2;
    _Float16*       W2pk = (_Float16*)ws;         ws += 6 * 4 * 64 * 8 * 2;
    _Float16*       uW1pk= (_Float16*)ws;         ws += 4 * 12 * 64 * 8 * 2;
    _Float16*       uW2pk= (_Float16*)ws;         ws += 6 * 8 * 64 * 8 * 2;
    int*            deg  = (int*)ws;              ws += (size_t)NPAD * 4;
    int*            cur  = (int*)ws;              ws += (size_t)NPAD * 4;
    int*            bsum = (int*)ws;              ws += 64 * 4;
    int2*           sJI  = (int2*)ws;             ws += (size_t)N_EDGES * 8;
    float*          sEC  = (float*)ws;            ws += (size_t)N_EDGES * 4;

    hipMemsetAsync(agg, 0, (size_t)NPAD * 64 * sizeof(float), stream);
    hipMemsetAsync(deg, 0, (size_t)NPAD * sizeof(int), stream);

    const int packGrid = (N_EDGES + 255) / 256;  // covers pack work (612864) too
    k_pack<<<packGrid, 256, 0, stream>>>(x, ids, mW1, mW2, uW1, uW2, ei, deg,
                                         Xid, W1pk, W2pk, uW1pk, uW2pk);
    k_scan1<<<NCHUNK, 64, 0, stream>>>(deg, bsum);
    k_scan3<<<NCHUNK, 1024, 0, stream>>>(deg, bsum, cur);
    k_mid<<<SCAT_BLK + PRE_BLK, 256, 0, stream>>>(ei, ecv, cur, sJI, sEC,
                                                  Xid, W1pk, mb1, P1, P2);
    k_edge<<<NBLK_E, 256, 0, stream>>>(sJI, sEC, P1, P2, W2pk, mb2, agg);
    k_upd<<<NPAD / 64, 256, 0, stream>>>(Xid, ncv, agg, uW1pk, ub1, uW2pk, ub2, out);
}

// Round 14
// 234.062 us; speedup vs baseline: 3.6880x; 1.0577x over previous
//
#include <hip/hip_runtime.h>

#define N_NODES 50000
#define N_EDGES 800000
#define NPAD    50048   // nodes padded to multiple of 64
#define NCHUNK  49      // ceil(NPAD/1024)

// k_edge span geometry (FROZEN, known-good): 1250 blocks * 4 waves * 160 edges
#define EPWAVE 160      // edges per wave (contiguous in sorted order)
#define SLEN   40       // edges per stream (4 streams per wave, one per kg)
#define NITER  10       // SLEN/4 group-iterations per wave (even, for unroll-2)
#define NBLK_E 1250

#define SCAT_BLK 3125   // k_mid blocks doing scatter (+agg zero) (800000/256)
#define PRE_BLK  782    // k_mid blocks doing pre (NPAD/64)

typedef __attribute__((ext_vector_type(8))) _Float16 f16x8;
typedef __attribute__((ext_vector_type(4))) float f32x4;

// ---------------------------------------------------------------------------
// k_pack: prepack ALL weights into MFMA B-fragment order (f16) + histogram of
// edge targets into deg[]. (Xid packing moved into k_mid's pre range.)
// ---------------------------------------------------------------------------
__global__ __launch_bounds__(256) void k_pack(const float* __restrict__ mW1,
                                              const float* __restrict__ mW2,
                                              const float* __restrict__ uW1,
                                              const float* __restrict__ uW2,
                                              const int* __restrict__ ei,
                                              int* __restrict__ deg,
                                              _Float16* __restrict__ W1pk,
                                              _Float16* __restrict__ W2pk,
                                              _Float16* __restrict__ uW1pk,
                                              _Float16* __restrict__ uW2pk) {
    const int tid = blockIdx.x * 256 + threadIdx.x;
    if (tid < N_EDGES) atomicAdd(&deg[ei[N_EDGES + tid]], 1);

    int r = tid;
    if (r < 3 * 24 * 64) {  // msg-W1, K=96, NT=24 (cols 0..191 P1, 192..383 P2)
        const int kt = r / (24 * 64), nt = (r / 64) % 24, l = r % 64;
        const int e = l & 15, kg = l >> 4;
        f16x8 v;
#pragma unroll
        for (int i = 0; i < 8; ++i) {
            const int k = kt * 32 + kg * 8 + i;
            const int col = nt * 16 + e;
            float val;
            if (col < 192) { const int row = (k < 64) ? k : k + 64;  val = mW1[row * 192 + col]; }
            else           { const int row = (k < 64) ? k + 64 : k + 96; val = mW1[row * 192 + (col - 192)]; }
            v[i] = (_Float16)val;
        }
        *(f16x8*)&W1pk[r * 8] = v;
        return;
    }
    r -= 3 * 24 * 64;
    if (r < 6 * 4 * 64) {  // msg-W2 [192,64]
        const int kt = r / (4 * 64), nt = (r / 64) % 4, l = r % 64;
        const int e = l & 15, kg = l >> 4;
        f16x8 v;
#pragma unroll
        for (int i = 0; i < 8; ++i)
            v[i] = (_Float16)mW2[(kt * 32 + kg * 8 + i) * 64 + nt * 16 + e];
        *(f16x8*)&W2pk[r * 8] = v;
        return;
    }
    r -= 6 * 4 * 64;
    if (r < 4 * 12 * 64) {  // uW1 [128,192]
        const int kt = r / (12 * 64), nt = (r / 64) % 12, l = r % 64;
        const int e = l & 15, kg = l >> 4;
        f16x8 v;
#pragma unroll
        for (int i = 0; i < 8; ++i)
            v[i] = (_Float16)uW1[(kt * 32 + kg * 8 + i) * 192 + nt * 16 + e];
        *(f16x8*)&uW1pk[r * 8] = v;
        return;
    }
    r -= 4 * 12 * 64;
    if (r < 6 * 8 * 64) {  // uW2 [192,128]
        const int kt = r / (8 * 64), nt = (r / 64) % 8, l = r % 64;
        const int e = l & 15, kg = l >> 4;
        f16x8 v;
#pragma unroll
        for (int i = 0; i < 8; ++i)
            v[i] = (_Float16)uW2[(kt * 32 + kg * 8 + i) * 128 + nt * 16 + e];
        *(f16x8*)&uW2pk[r * 8] = v;
    }
}

// ---------------------------------------------------------------------------
// k_scan (fused): each block computes its own base = sum(deg[0 .. bid*1024))
// by grid-stride + wave reduce (integer adds -> deterministic, identical to
// the old scan1+scan3 result), then the verbatim local inclusive scan.
// ---------------------------------------------------------------------------
__global__ __launch_bounds__(1024) void k_scan(const int* __restrict__ deg,
                                               int* __restrict__ cursor) {
    __shared__ int wtot[16];
    __shared__ int pre[16];
    const int t = threadIdx.x, w = t >> 6, lane = t & 63;

    // block base partials
    int partial = 0;
    const int lim = blockIdx.x * 1024;
    for (int i = t; i < lim; i += 1024) partial += deg[i];
#pragma unroll
    for (int off = 32; off; off >>= 1) partial += __shfl_xor(partial, off);
    if (lane == 0) pre[w] = partial;

    // local inclusive scan (verbatim)
    const int i = blockIdx.x * 1024 + t;
    const int v0 = (i < NPAD) ? deg[i] : 0;
    int v = v0;
#pragma unroll
    for (int off = 1; off < 64; off <<= 1) {
        const int n = __shfl_up(v, off);
        if (lane >= off) v += n;
    }
    if (lane == 63) wtot[w] = v;
    __syncthreads();

    int base = 0;
#pragma unroll
    for (int q = 0; q < 16; ++q) base += pre[q];
    for (int q = 0; q < w; ++q) base += wtot[q];
    if (i < NPAD) cursor[i] = base + v - v0;
}

// ---------------------------------------------------------------------------
// k_mid: merged independent work.
//  blocks [0, SCAT_BLK): zero agg (float4) + scatter edges into target-sorted
//    order (verbatim scatter body).
//  blocks [SCAT_BLK, SCAT_BLK+PRE_BLK): pre — [P1|P2] = [x|id]@W1p (+b1),
//    reading x/ids f32 directly (values identical to the old Xid path) and
//    emitting Xid64 (f16 x-part, 64 cols) for k_upd.
// ---------------------------------------------------------------------------
__global__ __launch_bounds__(256) void k_mid(const int* __restrict__ ei,
                                             const float* __restrict__ ec,
                                             int* __restrict__ cursor,
                                             int2* __restrict__ sJI,
                                             float* __restrict__ sEC,
                                             const float* __restrict__ x,
                                             const float* __restrict__ ids,
                                             const _Float16* __restrict__ W1pk,
                                             const float* __restrict__ b1,
                                             _Float16* __restrict__ P1,
                                             _Float16* __restrict__ P2,
                                             _Float16* __restrict__ Xid64,
                                             float* __restrict__ agg) {
    if (blockIdx.x < SCAT_BLK) {
        const int e = blockIdx.x * 256 + threadIdx.x;  // e < 800000 always
        // zero agg: NPAD*64 = 3203072 floats = 800000*4 + 768*4
        const float4 z = {0.f, 0.f, 0.f, 0.f};
        *(float4*)&agg[e * 4] = z;
        if (e < 768) *(float4*)&agg[3200000 + e * 4] = z;
        // scatter (verbatim)
        const int i = ei[N_EDGES + e];
        const int pos = atomicAdd(&cursor[i], 1);
        sJI[pos] = make_int2(ei[e], i);
        sEC[pos] = ec[e];
        return;
    }
    // ---- pre body ----
    const int bid = blockIdx.x - SCAT_BLK;
    const int t = threadIdx.x, w = t >> 6, l = t & 63;
    const int e = l & 15, kg = l >> 4;
    const int n0 = bid * 64 + w * 16;
    const int node = n0 + e;
    const bool valid = node < N_NODES;

    f16x8 A[3];
#pragma unroll
    for (int kt = 0; kt < 3; ++kt) {
        float4 f0 = {0.f, 0.f, 0.f, 0.f}, f1 = {0.f, 0.f, 0.f, 0.f};
        if (valid) {
            if (kt < 2) {
                f0 = *(const float4*)&x[node * 64 + kt * 32 + kg * 8];
                f1 = *(const float4*)&x[node * 64 + kt * 32 + kg * 8 + 4];
            } else {
                f0 = *(const float4*)&ids[node * 32 + kg * 8];
                f1 = *(const float4*)&ids[node * 32 + kg * 8 + 4];
            }
        }
        f16x8 v;
        v[0] = (_Float16)f0.x; v[1] = (_Float16)f0.y; v[2] = (_Float16)f0.z; v[3] = (_Float16)f0.w;
        v[4] = (_Float16)f1.x; v[5] = (_Float16)f1.y; v[6] = (_Float16)f1.z; v[7] = (_Float16)f1.w;
        A[kt] = v;
        if (kt < 2) *(f16x8*)&Xid64[node * 64 + kt * 32 + kg * 8] = v;  // node < NPAD always
    }

#pragma unroll
    for (int nt = 0; nt < 24; ++nt) {
        const float bv = (nt < 12) ? b1[nt * 16 + e] : 0.f;
        f32x4 acc = {bv, bv, bv, bv};
#pragma unroll
        for (int kt = 0; kt < 3; ++kt) {
            const f16x8 B = *(const f16x8*)&W1pk[((kt * 24 + nt) * 64 + l) * 8];
            acc = __builtin_amdgcn_mfma_f32_16x16x32_f16(A[kt], B, acc, 0, 0, 0);
        }
#pragma unroll
        for (int r = 0; r < 4; ++r) {
            const int onode = n0 + kg * 4 + r;
            if (onode < N_NODES) {
                if (nt < 12) P1[onode * 192 + nt * 16 + e] = (_Float16)acc[r];
                else         P2[onode * 192 + (nt - 12) * 16 + e] = (_Float16)acc[r];
            }
        }
    }
}

// ---------------------------------------------------------------------------
// k_edge (MFMA f16, target-sorted, stream-per-quarter, ping-pong pipelined):
// FROZEN R8/R12/R13 structure — byte-identical. Wave owns 160 contiguous
// sorted edges = 4 streams of 40. h = ReLU(P1[i]+P2[j]) via pk f16 ops.
// Segmented register accumulation; atomic flush only on target change.
// ---------------------------------------------------------------------------
union U16 { uint4 q; f16x8 f; };

#define EDGE_LOAD(A1, A2, JIV)                                                  \
  {                                                                             \
    const _Float16* r1 = P1 + (size_t)(JIV).y * 192 + kg * 8;                   \
    const _Float16* r2 = P2 + (size_t)(JIV).x * 192 + kg * 8;                   \
    _Pragma("unroll")                                                           \
    for (int tt = 0; tt < 6; ++tt) {                                            \
      A1[tt] = *(const uint4*)(r1 + tt * 32);                                   \
      A2[tt] = *(const uint4*)(r2 + tt * 32);                                   \
    }                                                                           \
  }

#define EDGE_COMPUTE(A1, A2, IIV, ITER)                                         \
  {                                                                             \
    f32x4 acc0 = {0.f,0.f,0.f,0.f}, acc1 = {0.f,0.f,0.f,0.f};                   \
    f32x4 acc2 = {0.f,0.f,0.f,0.f}, acc3 = {0.f,0.f,0.f,0.f};                   \
    _Pragma("unroll")                                                           \
    for (int tt = 0; tt < 6; ++tt) {                                            \
      U16 a1, a2;                                                               \
      a1.q = A1[tt]; a2.q = A2[tt];                                             \
      f16x8 hh = a1.f + a2.f;                                                   \
      hh = __builtin_elementwise_max(hh, (f16x8)(_Float16)0.f);                 \
      acc0 = __builtin_amdgcn_mfma_f32_16x16x32_f16(hh, *(const f16x8*)&w2s[(tt*4+0)*64 + l], acc0, 0, 0, 0); \
      acc1 = __builtin_amdgcn_mfma_f32_16x16x32_f16(hh, *(const f16x8*)&w2s[(tt*4+1)*64 + l], acc1, 0, 0, 0); \
      acc2 = __builtin_amdgcn_mfma_f32_16x16x32_f16(hh, *(const f16x8*)&w2s[(tt*4+2)*64 + l], acc2, 0, 0, 0); \
      acc3 = __builtin_amdgcn_mfma_f32_16x16x32_f16(hh, *(const f16x8*)&w2s[(tt*4+3)*64 + l], acc3, 0, 0, 0); \
    }                                                                           \
    const float4 ecq = *(const float4*)(sEC + oBase + (ITER) * 4);              \
    _Pragma("unroll")                                                           \
    for (int r = 0; r < 4; ++r) {                                               \
      const int tr = __shfl((IIV), kg * 4 + r);                                 \
      if (tr != curT) {                                                         \
        if (curT >= 0) {                                                        \
          float* fb = agg + (size_t)curT * 64 + e;                              \
          atomicAdd(fb,      s0); atomicAdd(fb + 16, s1);                       \
          atomicAdd(fb + 32, s2); atomicAdd(fb + 48, s3);                       \
        }                                                                       \
        s0 = s1 = s2 = s3 = 0.f;                                                \
        curT = tr;                                                              \
      }                                                                         \
      const float ecv = ((const float*)&ecq)[r];                                \
      s0 += (acc0[r] + b2v[0]) * ecv;                                           \
      s1 += (acc1[r] + b2v[1]) * ecv;                                           \
      s2 += (acc2[r] + b2v[2]) * ecv;                                           \
      s3 += (acc3[r] + b2v[3]) * ecv;                                           \
    }                                                                           \
  }

__global__ __launch_bounds__(256) void k_edge(const int2* __restrict__ sJI,
                                              const float* __restrict__ sEC,
                                              const _Float16* __restrict__ P1,
                                              const _Float16* __restrict__ P2,
                                              const _Float16* __restrict__ W2pk,
                                              const float* __restrict__ b2,
                                              float* __restrict__ agg) {
    __shared__ uint4 w2s[6 * 4 * 64];  // 24576 B, f16 fragment-ordered
    const int t = threadIdx.x;
    for (int v = t; v < 1536; v += 256) w2s[v] = ((const uint4*)W2pk)[v];
    __syncthreads();

    const int w = t >> 6, l = t & 63;
    const int e = l & 15, kg = l >> 4;
    float b2v[4];
#pragma unroll
    for (int n = 0; n < 4; ++n) b2v[n] = b2[n * 16 + e];

    const int waveBase = (blockIdx.x * 4 + w) * EPWAVE;
    const int aBase = waveBase + (e >> 2) * SLEN + (e & 3);  // A-side edge per lane
    const int oBase = waveBase + kg * SLEN;                  // output stream per quarter

    int curT = -1;
    float s0 = 0.f, s1 = 0.f, s2 = 0.f, s3 = 0.f;

    int2 jiA = sJI[aBase];
    uint4 A1a[6], A2a[6], A1b[6], A2b[6];
    EDGE_LOAD(A1a, A2a, jiA);

    for (int it = 0; it < NITER; it += 2) {
        const int2 jiB = sJI[aBase + (it + 1) * 4];
        EDGE_LOAD(A1b, A2b, jiB);
        EDGE_COMPUTE(A1a, A2a, jiA.y, it);
        if (it + 2 < NITER) {
            jiA = sJI[aBase + (it + 2) * 4];
            EDGE_LOAD(A1a, A2a, jiA);
        }
        EDGE_COMPUTE(A1b, A2b, jiB.y, it + 1);
    }
    {
        float* fb = agg + (size_t)curT * 64 + e;
        atomicAdd(fb,      s0); atomicAdd(fb + 16, s1);
        atomicAdd(fb + 32, s2); atomicAdd(fb + 48, s3);
    }
}

// ---------------------------------------------------------------------------
// k_upd (fused MFMA f16): H = ReLU([x*nc|agg]@uW1+b1) in swizzled LDS, then
// out = H@uW2+b2. x-part from Xid64 (f16, 64 cols, written by k_mid pre).
// ---------------------------------------------------------------------------
__global__ __launch_bounds__(256) void k_upd(const _Float16* __restrict__ Xid64,
                                             const float* __restrict__ nc,
                                             const float* __restrict__ agg,
                                             const _Float16* __restrict__ uW1pk,
                                             const float* __restrict__ ub1,
                                             const _Float16* __restrict__ uW2pk,
                                             const float* __restrict__ ub2,
                                             float* __restrict__ out) {
    __shared__ char Hs[4][16 * 384];
    const int t = threadIdx.x, w = t >> 6, l = t & 63;
    const int e = l & 15, kg = l >> 4;
    const int n0 = blockIdx.x * 64 + w * 16;
    const int nodeA = n0 + e;

    const float ncv = nc[nodeA < N_NODES ? nodeA : N_NODES - 1];
    f16x8 A[4];
#pragma unroll
    for (int kt = 0; kt < 2; ++kt) {
        const f16x8 xa = *(const f16x8*)&Xid64[nodeA * 64 + kt * 32 + kg * 8];
        f16x8 o;
#pragma unroll
        for (int i = 0; i < 8; ++i) o[i] = (_Float16)((float)xa[i] * ncv);
        A[kt] = o;
    }
#pragma unroll
    for (int kt = 2; kt < 4; ++kt) {
        const float* ap = agg + (size_t)nodeA * 64 + (kt - 2) * 32 + kg * 8;
        const float4 a0 = *(const float4*)ap;
        const float4 a1 = *(const float4*)(ap + 4);
        f16x8 o;
        o[0] = (_Float16)a0.x; o[1] = (_Float16)a0.y; o[2] = (_Float16)a0.z; o[3] = (_Float16)a0.w;
        o[4] = (_Float16)a1.x; o[5] = (_Float16)a1.y; o[6] = (_Float16)a1.z; o[7] = (_Float16)a1.w;
        A[kt] = o;
    }

#pragma unroll
    for (int nt = 0; nt < 12; ++nt) {
        const float bv = ub1[nt * 16 + e];
        f32x4 acc = {bv, bv, bv, bv};
#pragma unroll
        for (int kt = 0; kt < 4; ++kt) {
            const f16x8 B = *(const f16x8*)&uW1pk[((kt * 12 + nt) * 64 + l) * 8];
            acc = __builtin_amdgcn_mfma_f32_16x16x32_f16(A[kt], B, acc, 0, 0, 0);
        }
#pragma unroll
        for (int r = 0; r < 4; ++r) {
            const int hr = kg * 4 + r;
            const float v = acc[r] > 0.f ? acc[r] : 0.f;
            int byte = hr * 384 + (nt * 16 + e) * 2;
            byte ^= (hr & 7) << 4;
            *(_Float16*)(&Hs[w][0] + byte) = (_Float16)v;
        }
    }

    f16x8 A2[6];
#pragma unroll
    for (int kt = 0; kt < 6; ++kt) {
        int byte = e * 384 + kt * 64 + kg * 16;
        byte ^= (e & 7) << 4;
        A2[kt] = *(const f16x8*)(&Hs[w][0] + byte);
    }
#pragma unroll
    for (int nt = 0; nt < 8; ++nt) {
        const float bv = ub2[nt * 16 + e];
        f32x4 acc = {bv, bv, bv, bv};
#pragma unroll
        for (int kt = 0; kt < 6; ++kt) {
            const f16x8 B = *(const f16x8*)&uW2pk[((kt * 8 + nt) * 64 + l) * 8];
            acc = __builtin_amdgcn_mfma_f32_16x16x32_f16(A2[kt], B, acc, 0, 0, 0);
        }
#pragma unroll
        for (int r = 0; r < 4; ++r) {
            const int node = n0 + kg * 4 + r;
            if (node < N_NODES) out[node * 128 + nt * 16 + e] = acc[r];
        }
    }
}

extern "C" void kernel_launch(void* const* d_in, const int* in_sizes, int n_in,
                              void* d_out, int out_size, void* d_ws, size_t ws_size,
                              hipStream_t stream) {
    const float* x   = (const float*)d_in[0];
    const int*   ei  = (const int*)d_in[1];
    const float* ncv = (const float*)d_in[2];
    const float* ecv = (const float*)d_in[3];
    const float* ids = (const float*)d_in[4];
    const float* mW1 = (const float*)d_in[6];
    const float* mb1 = (const float*)d_in[7];
    const float* mW2 = (const float*)d_in[8];
    const float* mb2 = (const float*)d_in[9];
    const float* uW1 = (const float*)d_in[10];
    const float* ub1 = (const float*)d_in[11];
    const float* uW2 = (const float*)d_in[12];
    const float* ub2 = (const float*)d_in[13];
    float* out = (float*)d_out;

    char* ws = (char*)d_ws;
    _Float16*       Xid64= (_Float16*)ws;         ws += (size_t)NPAD * 64 * 2;
    _Float16*       P1   = (_Float16*)ws;         ws += (size_t)NPAD * 192 * 2;
    _Float16*       P2   = (_Float16*)ws;         ws += (size_t)NPAD * 192 * 2;
    float*          agg  = (float*)ws;            ws += (size_t)NPAD * 64 * 4;
    _Float16*       W1pk = (_Float16*)ws;         ws += 3 * 24 * 64 * 8 * 2;
    _Float16*       W2pk = (_Float16*)ws;         ws += 6 * 4 * 64 * 8 * 2;
    _Float16*       uW1pk= (_Float16*)ws;         ws += 4 * 12 * 64 * 8 * 2;
    _Float16*       uW2pk= (_Float16*)ws;         ws += 6 * 8 * 64 * 8 * 2;
    int*            deg  = (int*)ws;              ws += (size_t)NPAD * 4;
    int*            cur  = (int*)ws;              ws += (size_t)NPAD * 4;
    int2*           sJI  = (int2*)ws;             ws += (size_t)N_EDGES * 8;
    float*          sEC  = (float*)ws;            ws += (size_t)N_EDGES * 4;

    hipMemsetAsync(deg, 0, (size_t)NPAD * sizeof(int), stream);

    k_pack<<<(N_EDGES + 255) / 256, 256, 0, stream>>>(mW1, mW2, uW1, uW2, ei, deg,
                                                      W1pk, W2pk, uW1pk, uW2pk);
    k_scan<<<NCHUNK, 1024, 0, stream>>>(deg, cur);
    k_mid<<<SCAT_BLK + PRE_BLK, 256, 0, stream>>>(ei, ecv, cur, sJI, sEC,
                                                  x, ids, W1pk, mb1, P1, P2,
                                                  Xid64, agg);
    k_edge<<<NBLK_E, 256, 0, stream>>>(sJI, sEC, P1, P2, W2pk, mb2, agg);
    k_upd<<<PRE_BLK, 256, 0, stream>>>(Xid64, ncv, agg, uW1pk, ub1, uW2pk, ub2, out);
}

// Round 16
// 233.949 us; speedup vs baseline: 3.6898x; 1.0005x over previous
//
#include <hip/hip_runtime.h>

#define N_NODES 50000
#define N_EDGES 800000
#define NPAD    50048   // nodes padded to multiple of 64
#define NCHUNK  49      // ceil(NPAD/1024)

// k_edge span geometry (FROZEN, known-good): 1250 blocks * 4 waves * 160 edges
#define EPWAVE 160      // edges per wave (contiguous in sorted order)
#define SLEN   40       // edges per stream (4 streams per wave, one per kg)
#define NITER  10       // SLEN/4 group-iterations per wave (even, for unroll-2)
#define NBLK_E 1250

#define SCAT_BLK 3125   // k_mid blocks doing scatter (+agg zero) (800000/256)
#define PRE_BLK  782    // k_mid blocks doing pre (NPAD/64)

typedef __attribute__((ext_vector_type(8))) _Float16 f16x8;
typedef __attribute__((ext_vector_type(4))) float f32x4;

// ---------------------------------------------------------------------------
// k_pack: prepack ALL weights into MFMA B-fragment order (f16) + histogram of
// edge targets into deg[]. (Xid packing lives in k_mid's pre range.)
// ---------------------------------------------------------------------------
__global__ __launch_bounds__(256) void k_pack(const float* __restrict__ mW1,
                                              const float* __restrict__ mW2,
                                              const float* __restrict__ uW1,
                                              const float* __restrict__ uW2,
                                              const int* __restrict__ ei,
                                              int* __restrict__ deg,
                                              _Float16* __restrict__ W1pk,
                                              _Float16* __restrict__ W2pk,
                                              _Float16* __restrict__ uW1pk,
                                              _Float16* __restrict__ uW2pk) {
    const int tid = blockIdx.x * 256 + threadIdx.x;
    if (tid < N_EDGES) atomicAdd(&deg[ei[N_EDGES + tid]], 1);

    int r = tid;
    if (r < 3 * 24 * 64) {  // msg-W1, K=96, NT=24 (cols 0..191 P1, 192..383 P2)
        const int kt = r / (24 * 64), nt = (r / 64) % 24, l = r % 64;
        const int e = l & 15, kg = l >> 4;
        f16x8 v;
#pragma unroll
        for (int i = 0; i < 8; ++i) {
            const int k = kt * 32 + kg * 8 + i;
            const int col = nt * 16 + e;
            float val;
            if (col < 192) { const int row = (k < 64) ? k : k + 64;  val = mW1[row * 192 + col]; }
            else           { const int row = (k < 64) ? k + 64 : k + 96; val = mW1[row * 192 + (col - 192)]; }
            v[i] = (_Float16)val;
        }
        *(f16x8*)&W1pk[r * 8] = v;
        return;
    }
    r -= 3 * 24 * 64;
    if (r < 6 * 4 * 64) {  // msg-W2 [192,64]
        const int kt = r / (4 * 64), nt = (r / 64) % 4, l = r % 64;
        const int e = l & 15, kg = l >> 4;
        f16x8 v;
#pragma unroll
        for (int i = 0; i < 8; ++i)
            v[i] = (_Float16)mW2[(kt * 32 + kg * 8 + i) * 64 + nt * 16 + e];
        *(f16x8*)&W2pk[r * 8] = v;
        return;
    }
    r -= 6 * 4 * 64;
    if (r < 4 * 12 * 64) {  // uW1 [128,192]
        const int kt = r / (12 * 64), nt = (r / 64) % 12, l = r % 64;
        const int e = l & 15, kg = l >> 4;
        f16x8 v;
#pragma unroll
        for (int i = 0; i < 8; ++i)
            v[i] = (_Float16)uW1[(kt * 32 + kg * 8 + i) * 192 + nt * 16 + e];
        *(f16x8*)&uW1pk[r * 8] = v;
        return;
    }
    r -= 4 * 12 * 64;
    if (r < 6 * 8 * 64) {  // uW2 [192,128]
        const int kt = r / (8 * 64), nt = (r / 64) % 8, l = r % 64;
        const int e = l & 15, kg = l >> 4;
        f16x8 v;
#pragma unroll
        for (int i = 0; i < 8; ++i)
            v[i] = (_Float16)uW2[(kt * 32 + kg * 8 + i) * 128 + nt * 16 + e];
        *(f16x8*)&uW2pk[r * 8] = v;
    }
}

// ---------------------------------------------------------------------------
// k_scan (fused): each block computes its own base = sum(deg[0 .. bid*1024))
// by grid-stride + wave reduce (integer adds -> deterministic), then the
// local inclusive scan.
// ---------------------------------------------------------------------------
__global__ __launch_bounds__(1024) void k_scan(const int* __restrict__ deg,
                                               int* __restrict__ cursor) {
    __shared__ int wtot[16];
    __shared__ int pre[16];
    const int t = threadIdx.x, w = t >> 6, lane = t & 63;

    // block base partials
    int partial = 0;
    const int lim = blockIdx.x * 1024;
    for (int i = t; i < lim; i += 1024) partial += deg[i];
#pragma unroll
    for (int off = 32; off; off >>= 1) partial += __shfl_xor(partial, off);
    if (lane == 0) pre[w] = partial;

    // local inclusive scan
    const int i = blockIdx.x * 1024 + t;
    const int v0 = (i < NPAD) ? deg[i] : 0;
    int v = v0;
#pragma unroll
    for (int off = 1; off < 64; off <<= 1) {
        const int n = __shfl_up(v, off);
        if (lane >= off) v += n;
    }
    if (lane == 63) wtot[w] = v;
    __syncthreads();

    int base = 0;
#pragma unroll
    for (int q = 0; q < 16; ++q) base += pre[q];
    for (int q = 0; q < w; ++q) base += wtot[q];
    if (i < NPAD) cursor[i] = base + v - v0;
}

// ---------------------------------------------------------------------------
// k_mid: merged independent work.
//  blocks [0, SCAT_BLK): zero agg (float4) + scatter edges into target-sorted
//    order (verbatim scatter body).
//  blocks [SCAT_BLK, SCAT_BLK+PRE_BLK): pre — [P1|P2] = [x|id]@W1p (+b1),
//    reading x/ids f32 directly and emitting Xid64 (f16 x-part) for k_upd.
// ---------------------------------------------------------------------------
__global__ __launch_bounds__(256) void k_mid(const int* __restrict__ ei,
                                             const float* __restrict__ ec,
                                             int* __restrict__ cursor,
                                             int2* __restrict__ sJI,
                                             float* __restrict__ sEC,
                                             const float* __restrict__ x,
                                             const float* __restrict__ ids,
                                             const _Float16* __restrict__ W1pk,
                                             const float* __restrict__ b1,
                                             _Float16* __restrict__ P1,
                                             _Float16* __restrict__ P2,
                                             _Float16* __restrict__ Xid64,
                                             float* __restrict__ agg) {
    if (blockIdx.x < SCAT_BLK) {
        const int e = blockIdx.x * 256 + threadIdx.x;  // e < 800000 always
        // zero agg: NPAD*64 = 3203072 floats = 800000*4 + 768*4
        const float4 z = {0.f, 0.f, 0.f, 0.f};
        *(float4*)&agg[e * 4] = z;
        if (e < 768) *(float4*)&agg[3200000 + e * 4] = z;
        // scatter (verbatim)
        const int i = ei[N_EDGES + e];
        const int pos = atomicAdd(&cursor[i], 1);
        sJI[pos] = make_int2(ei[e], i);
        sEC[pos] = ec[e];
        return;
    }
    // ---- pre body ----
    const int bid = blockIdx.x - SCAT_BLK;
    const int t = threadIdx.x, w = t >> 6, l = t & 63;
    const int e = l & 15, kg = l >> 4;
    const int n0 = bid * 64 + w * 16;
    const int node = n0 + e;
    const bool valid = node < N_NODES;

    f16x8 A[3];
#pragma unroll
    for (int kt = 0; kt < 3; ++kt) {
        float4 f0 = {0.f, 0.f, 0.f, 0.f}, f1 = {0.f, 0.f, 0.f, 0.f};
        if (valid) {
            if (kt < 2) {
                f0 = *(const float4*)&x[node * 64 + kt * 32 + kg * 8];
                f1 = *(const float4*)&x[node * 64 + kt * 32 + kg * 8 + 4];
            } else {
                f0 = *(const float4*)&ids[node * 32 + kg * 8];
                f1 = *(const float4*)&ids[node * 32 + kg * 8 + 4];
            }
        }
        f16x8 v;
        v[0] = (_Float16)f0.x; v[1] = (_Float16)f0.y; v[2] = (_Float16)f0.z; v[3] = (_Float16)f0.w;
        v[4] = (_Float16)f1.x; v[5] = (_Float16)f1.y; v[6] = (_Float16)f1.z; v[7] = (_Float16)f1.w;
        A[kt] = v;
        if (kt < 2) *(f16x8*)&Xid64[node * 64 + kt * 32 + kg * 8] = v;  // node < NPAD always
    }

#pragma unroll
    for (int nt = 0; nt < 24; ++nt) {
        const float bv = (nt < 12) ? b1[nt * 16 + e] : 0.f;
        f32x4 acc = {bv, bv, bv, bv};
#pragma unroll
        for (int kt = 0; kt < 3; ++kt) {
            const f16x8 B = *(const f16x8*)&W1pk[((kt * 24 + nt) * 64 + l) * 8];
            acc = __builtin_amdgcn_mfma_f32_16x16x32_f16(A[kt], B, acc, 0, 0, 0);
        }
#pragma unroll
        for (int r = 0; r < 4; ++r) {
            const int onode = n0 + kg * 4 + r;
            if (onode < N_NODES) {
                if (nt < 12) P1[onode * 192 + nt * 16 + e] = (_Float16)acc[r];
                else         P2[onode * 192 + (nt - 12) * 16 + e] = (_Float16)acc[r];
            }
        }
    }
}

// ---------------------------------------------------------------------------
// k_edge (MFMA f16, target-sorted, stream-per-quarter, ping-pong pipelined):
// FROZEN R8/R12/R13/R14 structure — byte-identical. Wave owns 160 contiguous
// sorted edges = 4 streams of 40. h = ReLU(P1[i]+P2[j]) via pk f16 ops.
// Segmented register accumulation; atomic flush only on target change.
// ---------------------------------------------------------------------------
union U16 { uint4 q; f16x8 f; };

#define EDGE_LOAD(A1, A2, JIV)                                                  \
  {                                                                             \
    const _Float16* r1 = P1 + (size_t)(JIV).y * 192 + kg * 8;                   \
    const _Float16* r2 = P2 + (size_t)(JIV).x * 192 + kg * 8;                   \
    _Pragma("unroll")                                                           \
    for (int tt = 0; tt < 6; ++tt) {                                            \
      A1[tt] = *(const uint4*)(r1 + tt * 32);                                   \
      A2[tt] = *(const uint4*)(r2 + tt * 32);                                   \
    }                                                                           \
  }

#define EDGE_COMPUTE(A1, A2, IIV, ITER)                                         \
  {                                                                             \
    f32x4 acc0 = {0.f,0.f,0.f,0.f}, acc1 = {0.f,0.f,0.f,0.f};                   \
    f32x4 acc2 = {0.f,0.f,0.f,0.f}, acc3 = {0.f,0.f,0.f,0.f};                   \
    _Pragma("unroll")                                                           \
    for (int tt = 0; tt < 6; ++tt) {                                            \
      U16 a1, a2;                                                               \
      a1.q = A1[tt]; a2.q = A2[tt];                                             \
      f16x8 hh = a1.f + a2.f;                                                   \
      hh = __builtin_elementwise_max(hh, (f16x8)(_Float16)0.f);                 \
      acc0 = __builtin_amdgcn_mfma_f32_16x16x32_f16(hh, *(const f16x8*)&w2s[(tt*4+0)*64 + l], acc0, 0, 0, 0); \
      acc1 = __builtin_amdgcn_mfma_f32_16x16x32_f16(hh, *(const f16x8*)&w2s[(tt*4+1)*64 + l], acc1, 0, 0, 0); \
      acc2 = __builtin_amdgcn_mfma_f32_16x16x32_f16(hh, *(const f16x8*)&w2s[(tt*4+2)*64 + l], acc2, 0, 0, 0); \
      acc3 = __builtin_amdgcn_mfma_f32_16x16x32_f16(hh, *(const f16x8*)&w2s[(tt*4+3)*64 + l], acc3, 0, 0, 0); \
    }                                                                           \
    const float4 ecq = *(const float4*)(sEC + oBase + (ITER) * 4);              \
    _Pragma("unroll")                                                           \
    for (int r = 0; r < 4; ++r) {                                               \
      const int tr = __shfl((IIV), kg * 4 + r);                                 \
      if (tr != curT) {                                                         \
        if (curT >= 0) {                                                        \
          float* fb = agg + (size_t)curT * 64 + e;                              \
          atomicAdd(fb,      s0); atomicAdd(fb + 16, s1);                       \
          atomicAdd(fb + 32, s2); atomicAdd(fb + 48, s3);                       \
        }                                                                       \
        s0 = s1 = s2 = s3 = 0.f;                                                \
        curT = tr;                                                              \
      }                                                                         \
      const float ecv = ((const float*)&ecq)[r];                                \
      s0 += (acc0[r] + b2v[0]) * ecv;                                           \
      s1 += (acc1[r] + b2v[1]) * ecv;                                           \
      s2 += (acc2[r] + b2v[2]) * ecv;                                           \
      s3 += (acc3[r] + b2v[3]) * ecv;                                           \
    }                                                                           \
  }

__global__ __launch_bounds__(256) void k_edge(const int2* __restrict__ sJI,
                                              const float* __restrict__ sEC,
                                              const _Float16* __restrict__ P1,
                                              const _Float16* __restrict__ P2,
                                              const _Float16* __restrict__ W2pk,
                                              const float* __restrict__ b2,
                                              float* __restrict__ agg) {
    __shared__ uint4 w2s[6 * 4 * 64];  // 24576 B, f16 fragment-ordered
    const int t = threadIdx.x;
    for (int v = t; v < 1536; v += 256) w2s[v] = ((const uint4*)W2pk)[v];
    __syncthreads();

    const int w = t >> 6, l = t & 63;
    const int e = l & 15, kg = l >> 4;
    float b2v[4];
#pragma unroll
    for (int n = 0; n < 4; ++n) b2v[n] = b2[n * 16 + e];

    const int waveBase = (blockIdx.x * 4 + w) * EPWAVE;
    const int aBase = waveBase + (e >> 2) * SLEN + (e & 3);  // A-side edge per lane
    const int oBase = waveBase + kg * SLEN;                  // output stream per quarter

    int curT = -1;
    float s0 = 0.f, s1 = 0.f, s2 = 0.f, s3 = 0.f;

    int2 jiA = sJI[aBase];
    uint4 A1a[6], A2a[6], A1b[6], A2b[6];
    EDGE_LOAD(A1a, A2a, jiA);

    for (int it = 0; it < NITER; it += 2) {
        const int2 jiB = sJI[aBase + (it + 1) * 4];
        EDGE_LOAD(A1b, A2b, jiB);
        EDGE_COMPUTE(A1a, A2a, jiA.y, it);
        if (it + 2 < NITER) {
            jiA = sJI[aBase + (it + 2) * 4];
            EDGE_LOAD(A1a, A2a, jiA);
        }
        EDGE_COMPUTE(A1b, A2b, jiB.y, it + 1);
    }
    {
        float* fb = agg + (size_t)curT * 64 + e;
        atomicAdd(fb,      s0); atomicAdd(fb + 16, s1);
        atomicAdd(fb + 32, s2); atomicAdd(fb + 48, s3);
    }
}

// ---------------------------------------------------------------------------
// k_upd (fused MFMA f16): H = ReLU([x*nc|agg]@uW1+b1) in swizzled LDS, then
// out = H@uW2+b2. x-part from Xid64 (f16, 64 cols, written by k_mid pre).
// ---------------------------------------------------------------------------
__global__ __launch_bounds__(256) void k_upd(const _Float16* __restrict__ Xid64,
                                             const float* __restrict__ nc,
                                             const float* __restrict__ agg,
                                             const _Float16* __restrict__ uW1pk,
                                             const float* __restrict__ ub1,
                                             const _Float16* __restrict__ uW2pk,
                                             const float* __restrict__ ub2,
                                             float* __restrict__ out) {
    __shared__ char Hs[4][16 * 384];
    const int t = threadIdx.x, w = t >> 6, l = t & 63;
    const int e = l & 15, kg = l >> 4;
    const int n0 = blockIdx.x * 64 + w * 16;
    const int nodeA = n0 + e;

    const float ncv = nc[nodeA < N_NODES ? nodeA : N_NODES - 1];
    f16x8 A[4];
#pragma unroll
    for (int kt = 0; kt < 2; ++kt) {
        const f16x8 xa = *(const f16x8*)&Xid64[nodeA * 64 + kt * 32 + kg * 8];
        f16x8 o;
#pragma unroll
        for (int i = 0; i < 8; ++i) o[i] = (_Float16)((float)xa[i] * ncv);
        A[kt] = o;
    }
#pragma unroll
    for (int kt = 2; kt < 4; ++kt) {
        const float* ap = agg + (size_t)nodeA * 64 + (kt - 2) * 32 + kg * 8;
        const float4 a0 = *(const float4*)ap;
        const float4 a1 = *(const float4*)(ap + 4);
        f16x8 o;
        o[0] = (_Float16)a0.x; o[1] = (_Float16)a0.y; o[2] = (_Float16)a0.z; o[3] = (_Float16)a0.w;
        o[4] = (_Float16)a1.x; o[5] = (_Float16)a1.y; o[6] = (_Float16)a1.z; o[7] = (_Float16)a1.w;
        A[kt] = o;
    }

#pragma unroll
    for (int nt = 0; nt < 12; ++nt) {
        const float bv = ub1[nt * 16 + e];
        f32x4 acc = {bv, bv, bv, bv};
#pragma unroll
        for (int kt = 0; kt < 4; ++kt) {
            const f16x8 B = *(const f16x8*)&uW1pk[((kt * 12 + nt) * 64 + l) * 8];
            acc = __builtin_amdgcn_mfma_f32_16x16x32_f16(A[kt], B, acc, 0, 0, 0);
        }
#pragma unroll
        for (int r = 0; r < 4; ++r) {
            const int hr = kg * 4 + r;
            const float v = acc[r] > 0.f ? acc[r] : 0.f;
            int byte = hr * 384 + (nt * 16 + e) * 2;
            byte ^= (hr & 7) << 4;
            *(_Float16*)(&Hs[w][0] + byte) = (_Float16)v;
        }
    }

    f16x8 A2[6];
#pragma unroll
    for (int kt = 0; kt < 6; ++kt) {
        int byte = e * 384 + kt * 64 + kg * 16;
        byte ^= (e & 7) << 4;
        A2[kt] = *(const f16x8*)(&Hs[w][0] + byte);
    }
#pragma unroll
    for (int nt = 0; nt < 8; ++nt) {
        const float bv = ub2[nt * 16 + e];
        f32x4 acc = {bv, bv, bv, bv};
#pragma unroll
        for (int kt = 0; kt < 6; ++kt) {
            const f16x8 B = *(const f16x8*)&uW2pk[((kt * 8 + nt) * 64 + l) * 8];
            acc = __builtin_amdgcn_mfma_f32_16x16x32_f16(A2[kt], B, acc, 0, 0, 0);
        }
#pragma unroll
        for (int r = 0; r < 4; ++r) {
            const int node = n0 + kg * 4 + r;
            if (node < N_NODES) out[node * 128 + nt * 16 + e] = acc[r];
        }
    }
}

extern "C" void kernel_launch(void* const* d_in, const int* in_sizes, int n_in,
                              void* d_out, int out_size, void* d_ws, size_t ws_size,
                              hipStream_t stream) {
    const float* x   = (const float*)d_in[0];
    const int*   ei  = (const int*)d_in[1];
    const float* ncv = (const float*)d_in[2];
    const float* ecv = (const float*)d_in[3];
    const float* ids = (const float*)d_in[4];
    const float* mW1 = (const float*)d_in[6];
    const float* mb1 = (const float*)d_in[7];
    const float* mW2 = (const float*)d_in[8];
    const float* mb2 = (const float*)d_in[9];
    const float* uW1 = (const float*)d_in[10];
    const float* ub1 = (const float*)d_in[11];
    const float* uW2 = (const float*)d_in[12];
    const float* ub2 = (const float*)d_in[13];
    float* out = (float*)d_out;

    char* ws = (char*)d_ws;
    _Float16*       Xid64= (_Float16*)ws;         ws += (size_t)NPAD * 64 * 2;
    _Float16*       P1   = (_Float16*)ws;         ws += (size_t)NPAD * 192 * 2;
    _Float16*       P2   = (_Float16*)ws;         ws += (size_t)NPAD * 192 * 2;
    float*          agg  = (float*)ws;            ws += (size_t)NPAD * 64 * 4;
    _Float16*       W1pk = (_Float16*)ws;         ws += 3 * 24 * 64 * 8 * 2;
    _Float16*       W2pk = (_Float16*)ws;         ws += 6 * 4 * 64 * 8 * 2;
    _Float16*       uW1pk= (_Float16*)ws;         ws += 4 * 12 * 64 * 8 * 2;
    _Float16*       uW2pk= (_Float16*)ws;         ws += 6 * 8 * 64 * 8 * 2;
    int*            deg  = (int*)ws;              ws += (size_t)NPAD * 4;
    int*            cur  = (int*)ws;              ws += (size_t)NPAD * 4;
    int2*           sJI  = (int2*)ws;             ws += (size_t)N_EDGES * 8;
    float*          sEC  = (float*)ws;            ws += (size_t)N_EDGES * 4;

    hipMemsetAsync(deg, 0, (size_t)NPAD * sizeof(int), stream);

    k_pack<<<(N_EDGES + 255) / 256, 256, 0, stream>>>(mW1, mW2, uW1, uW2, ei, deg,
                                                      W1pk, W2pk, uW1pk, uW2pk);
    k_scan<<<NCHUNK, 1024, 0, stream>>>(deg, cur);
    k_mid<<<SCAT_BLK + PRE_BLK, 256, 0, stream>>>(ei, ecv, cur, sJI, sEC,
                                                  x, ids, W1pk, mb1, P1, P2,
                                                  Xid64, agg);
    k_edge<<<NBLK_E, 256, 0, stream>>>(sJI, sEC, P1, P2, W2pk, mb2, agg);
    k_upd<<<PRE_BLK, 256, 0, stream>>>(Xid64, ncv, agg, uW1pk, ub1, uW2pk, ub2, out);
}